// Round 4
// baseline (258.009 us; speedup 1.0000x reference)
//
#include <hip/hip_runtime.h>
#include <hip/hip_fp16.h>
#include <math.h>

// GAT (2 layers) on MI355X — radix CSR + merged degree-bucketed aggregation.
// R1: gemm1/gemm2 MFMA (16x16x32 f16, fp32 accum).
// R2/R3: nontemporal stores/loads for streaming traffic (keep L2 for gather
//     tables) via ext_vector types, unroll-8 small-role gathers, scan_bkt
//     folded into scan_blk (last-block pattern).

#define NEG_SLOPE 0.2f
#define NBLKA 256
#define MAXNB 512
#define LDH 136   // padded halfs per LDS row

typedef _Float16 f16x8 __attribute__((ext_vector_type(8)));
typedef float f32x4 __attribute__((ext_vector_type(4)));
typedef unsigned int u32x4 __attribute__((ext_vector_type(4)));

__device__ __forceinline__ float leaky(float v) { return v > 0.f ? v : NEG_SLOPE * v; }

// ---------------- CSR build: radix partition by dst (+ W transpose prep) ----------------
__global__ __launch_bounds__(256) void histc_k(const int* __restrict__ ei, int E, int ET,
                                               int* __restrict__ blkpref, int NB,
                                               const float* __restrict__ W1,
                                               const float* __restrict__ W2,
                                               _Float16* __restrict__ w1t,
                                               _Float16* __restrict__ w2t,
                                               int* __restrict__ lcnt) {
  __shared__ int lhist[MAXNB];
  int chunk = (ET + NBLKA - 1) / NBLKA;
  int e0 = blockIdx.x * chunk, e1 = min(ET, e0 + chunk);
  for (int b = threadIdx.x; b < NB; b += 256) lhist[b] = 0;
  __syncthreads();
  for (int e = e0 + threadIdx.x; e < e1; e += 256) {
    int d = (e < E) ? __builtin_nontemporal_load(&ei[E + e]) : (e - E);
    atomicAdd(&lhist[d >> 7], 1);
  }
  __syncthreads();
  for (int b = threadIdx.x; b < NB; b += 256)
    blkpref[b * NBLKA + blockIdx.x] = lhist[b];
  // W1T [128n][128k], W2T [64n][128k] fp16 — block 0 only; also init last-block counter
  if (blockIdx.x == 0) {
    int t = threadIdx.x;
    if (t == 255) lcnt[31] = 0;
    if (t < 128) {
      union { _Float16 h[8]; u32x4 u; } buf;
      for (int k0 = 0; k0 < 128; k0 += 8) {
        #pragma unroll
        for (int u = 0; u < 8; ++u) buf.h[u] = (_Float16)W1[(k0 + u) * 128 + t];
        *(u32x4*)&w1t[t * 128 + k0] = buf.u;
      }
    } else if (t < 192) {
      int n = t - 128;
      union { _Float16 h[8]; u32x4 u; } buf;
      for (int k0 = 0; k0 < 128; k0 += 8) {
        #pragma unroll
        for (int u = 0; u < 8; ++u) buf.h[u] = (_Float16)W2[(k0 + u) * 64 + n];
        *(u32x4*)&w2t[n * 128 + k0] = buf.u;
      }
    }
  }
}

// scan within each bucket-row, then last block scans bucket bases (folded scan_bkt)
__global__ __launch_bounds__(256) void scan_blk_k(int* __restrict__ blkpref,
                                                  int* __restrict__ bbase,
                                                  int* __restrict__ lcnt,
                                                  int* __restrict__ rowptr,
                                                  int NB, int N, int ET) {
  __shared__ int sm[NBLKA];
  __shared__ int lastflag;
  int b = blockIdx.x, t = threadIdx.x;
  int v = blkpref[b * NBLKA + t];
  sm[t] = v;
  __syncthreads();
  #pragma unroll
  for (int off = 1; off < NBLKA; off <<= 1) {
    int x = (t >= off) ? sm[t - off] : 0;
    __syncthreads();
    sm[t] += x;
    __syncthreads();
  }
  blkpref[b * NBLKA + t] = sm[t] - v;
  if (t == NBLKA - 1) bbase[b] = sm[t];
  __threadfence();
  if (t == 0) lastflag = atomicAdd(&lcnt[31], 1);
  __syncthreads();
  if (lastflag != (int)gridDim.x - 1) return;
  // ---- last block: exclusive scan of bbase[0..NB-1] -> bbase[0..NB] ----
  int i0 = 2 * t, i1 = 2 * t + 1;
  int a = (i0 < NB) ? atomicAdd(&bbase[i0], 0) : 0;
  int c = (i1 < NB) ? atomicAdd(&bbase[i1], 0) : 0;
  __syncthreads();
  sm[t] = a + c;
  __syncthreads();
  #pragma unroll
  for (int off = 1; off < 256; off <<= 1) {
    int x = (t >= off) ? sm[t - off] : 0;
    __syncthreads();
    sm[t] += x;
    __syncthreads();
  }
  int base = sm[t] - (a + c);
  if (i0 <= NB) bbase[i0] = base;
  if (i1 <= NB) bbase[i1] = base + a;
  if (t == 0) { lcnt[0] = 0; lcnt[16] = 0; rowptr[N] = ET; }
}

__global__ __launch_bounds__(256) void passA_k(const int* __restrict__ ei, int E, int ET,
                                               const int* __restrict__ bbase,
                                               const int* __restrict__ blkpref,
                                               int* __restrict__ pairs, int NB) {
  __shared__ int lcur[MAXNB];
  int chunk = (ET + NBLKA - 1) / NBLKA;
  int e0 = blockIdx.x * chunk, e1 = min(ET, e0 + chunk);
  for (int b = threadIdx.x; b < NB; b += 256)
    lcur[b] = bbase[b] + blkpref[b * NBLKA + blockIdx.x];
  __syncthreads();
  for (int e = e0 + threadIdx.x; e < e1; e += 256) {
    int s, d;
    if (e < E) {
      s = __builtin_nontemporal_load(&ei[e]);
      d = __builtin_nontemporal_load(&ei[E + e]);
    } else { s = d = e - E; }
    int b = d >> 7;
    int pos = atomicAdd(&lcur[b], 1);
    __builtin_nontemporal_store(((d & 127) << 17) | s, &pairs[pos]);
  }
}

__global__ __launch_bounds__(256) void passB_k(const int* __restrict__ pairs,
                                               const int* __restrict__ bbase,
                                               int* __restrict__ rowptr,
                                               int* __restrict__ srcs,
                                               int* __restrict__ small_list,
                                               int* __restrict__ big_list,
                                               int* __restrict__ lcnt, int N) {
  __shared__ int ncnt[128], spre[128], lcur[128];
  __shared__ int wcS[2], wcB[2], bS, bB;
  int b = blockIdx.x, t = threadIdx.x;
  int nb0 = b << 7;
  int nn = min(128, N - nb0);
  int e0 = bbase[b], e1 = bbase[b + 1];
  if (t < 128) ncnt[t] = 0;
  __syncthreads();
  for (int r = e0 + t; r < e1; r += 256)
    atomicAdd(&ncnt[pairs[r] >> 17], 1);
  __syncthreads();
  if (t < 128) spre[t] = ncnt[t];
  __syncthreads();
  #pragma unroll
  for (int off = 1; off < 128; off <<= 1) {
    int x = (t < 128 && t >= off) ? spre[t - off] : 0;
    __syncthreads();
    if (t < 128) spre[t] += x;
    __syncthreads();
  }
  if (t < nn) {
    int base = e0 + spre[t] - ncnt[t];
    rowptr[nb0 + t] = base;
    lcur[t] = base;
  }
  __syncthreads();
  for (int r = e0 + t; r < e1; r += 256) {
    int p = pairs[r];
    int pos = atomicAdd(&lcur[p >> 17], 1);
    __builtin_nontemporal_store(p & 0x1FFFF, &srcs[pos]);
  }
  int lane = t & 63, wv = t >> 6;
  bool valid = (t < nn);
  int deg = valid ? ncnt[t] : 0;
  bool isS = valid && (deg <= 16);
  bool isB = valid && (deg > 16);
  unsigned long long ms = __ballot(isS);
  unsigned long long mb = __ballot(isB);
  if (lane == 0 && wv < 2) { wcS[wv] = __popcll(ms); wcB[wv] = __popcll(mb); }
  __syncthreads();
  if (t == 0) {
    bS = atomicAdd(&lcnt[0],  wcS[0] + wcS[1]);
    bB = atomicAdd(&lcnt[16], wcB[0] + wcB[1]);
  }
  __syncthreads();
  unsigned long long below = (lane == 0) ? 0ull : (~0ull >> (64 - lane));
  int offS = bS + ((wv == 1) ? wcS[0] : 0);
  int offB = bB + ((wv == 1) ? wcB[0] : 0);
  if (isS) small_list[offS + __popcll(ms & below)] = nb0 + t;
  if (isB) big_list[offB + __popcll(mb & below)]   = nb0 + t;
}

// ---------------- GEMM1 (MFMA) + alpha1: h1h = X(fp32) @ W1 ----------------
__global__ __launch_bounds__(256) void gemm1_k(const float* __restrict__ X,
                                               const _Float16* __restrict__ WT,
                                               const float* __restrict__ aw_s,
                                               const float* __restrict__ aw_d,
                                               __half* __restrict__ Hh,
                                               float* __restrict__ as,
                                               float* __restrict__ ad, int N) {
  __shared__ _Float16 xs[64 * LDH];    // X tile fp16 (also epilogue buffer)
  __shared__ _Float16 wt[128 * LDH];   // W1T tile [n][k]
  int t = threadIdx.x;
  int n0 = blockIdx.x * 64;
  for (int i = t; i < 2048; i += 256) {
    int r = i >> 4, c8 = i & 15;
    *(u32x4*)&wt[r * LDH + c8 * 8] = ((const u32x4*)WT)[i];
  }
  for (int i = t; i < 2048; i += 256) {
    int r = i >> 5, c4 = i & 31;
    int n = n0 + r;
    f32x4 xv = (n < N) ? __builtin_nontemporal_load(&((const f32x4*)X)[(size_t)n * 32 + c4])
                       : (f32x4){0.f, 0.f, 0.f, 0.f};
    __half2 h0 = __floats2half2_rn(xv[0], xv[1]);
    __half2 h1 = __floats2half2_rn(xv[2], xv[3]);
    uint2 u; u.x = *(unsigned*)&h0; u.y = *(unsigned*)&h1;
    *(uint2*)&xs[r * LDH + c4 * 4] = u;
  }
  __syncthreads();
  int wv = t >> 6, l = t & 63;
  int row16 = l & 15, kg = l >> 4;
  f32x4 acc[8];
  #pragma unroll
  for (int j = 0; j < 8; ++j) acc[j] = (f32x4){0.f, 0.f, 0.f, 0.f};
  #pragma unroll
  for (int kk = 0; kk < 4; ++kk) {
    int kbase = kk * 32 + kg * 8;
    f16x8 afr = *(f16x8*)&xs[(wv * 16 + row16) * LDH + kbase];
    #pragma unroll
    for (int j = 0; j < 8; ++j) {
      f16x8 bfr = *(f16x8*)&wt[(j * 16 + row16) * LDH + kbase];
      acc[j] = __builtin_amdgcn_mfma_f32_16x16x32_f16(afr, bfr, acc[j], 0, 0, 0);
    }
  }
  __syncthreads();
  #pragma unroll
  for (int j = 0; j < 8; ++j) {
    int col = j * 16 + row16;
    #pragma unroll
    for (int r = 0; r < 4; ++r) {
      int row = wv * 16 + kg * 4 + r;
      xs[row * LDH + col] = (_Float16)acc[j][r];
    }
  }
  __syncthreads();
  for (int i = t; i < 1024; i += 256) {
    int r = i >> 4, c8 = i & 15;
    int n = n0 + r;
    if (n < N)
      __builtin_nontemporal_store(*(u32x4*)&xs[r * LDH + c8 * 8],
                                  &((u32x4*)Hh)[(size_t)n * 16 + c8]);
  }
  {
    int r = t >> 2, h = t & 3;
    int n = n0 + r;
    float ps = 0.f, pd = 0.f;
    #pragma unroll
    for (int q = 0; q < 4; ++q) {
      f16x8 hv = *(f16x8*)&xs[r * LDH + h * 32 + q * 8];
      float4 s0 = *(const float4*)&aw_s[h * 32 + q * 8];
      float4 s1 = *(const float4*)&aw_s[h * 32 + q * 8 + 4];
      float4 d0 = *(const float4*)&aw_d[h * 32 + q * 8];
      float4 d1 = *(const float4*)&aw_d[h * 32 + q * 8 + 4];
      ps += (float)hv[0] * s0.x + (float)hv[1] * s0.y + (float)hv[2] * s0.z + (float)hv[3] * s0.w
          + (float)hv[4] * s1.x + (float)hv[5] * s1.y + (float)hv[6] * s1.z + (float)hv[7] * s1.w;
      pd += (float)hv[0] * d0.x + (float)hv[1] * d0.y + (float)hv[2] * d0.z + (float)hv[3] * d0.w
          + (float)hv[4] * d1.x + (float)hv[5] * d1.y + (float)hv[6] * d1.z + (float)hv[7] * d1.w;
    }
    if (n < N) { as[n * 4 + h] = ps; ad[n * 4 + h] = pd; }
  }
}

// ---------------- GEMM2 (MFMA) + alpha2: h2h = o1h(fp16) @ W2 ----------------
__global__ __launch_bounds__(256) void gemm2_k(const __half* __restrict__ X,
                                               const _Float16* __restrict__ WT,
                                               const float* __restrict__ aw_s,
                                               const float* __restrict__ aw_d,
                                               __half* __restrict__ Hh,
                                               float* __restrict__ as,
                                               float* __restrict__ ad, int N) {
  __shared__ _Float16 xs[64 * LDH];
  __shared__ _Float16 wt[64 * LDH];
  int t = threadIdx.x;
  int n0 = blockIdx.x * 64;
  for (int i = t; i < 1024; i += 256) {
    int r = i >> 4, c8 = i & 15;
    *(u32x4*)&wt[r * LDH + c8 * 8] = ((const u32x4*)WT)[i];
  }
  for (int i = t; i < 1024; i += 256) {
    int r = i >> 4, c8 = i & 15;
    int n = n0 + r;
    u32x4 v = (n < N) ? __builtin_nontemporal_load(&((const u32x4*)X)[(size_t)n * 16 + c8])
                      : (u32x4){0, 0, 0, 0};
    *(u32x4*)&xs[r * LDH + c8 * 8] = v;
  }
  __syncthreads();
  int wv = t >> 6, l = t & 63;
  int row16 = l & 15, kg = l >> 4;
  f32x4 acc[4];
  #pragma unroll
  for (int j = 0; j < 4; ++j) acc[j] = (f32x4){0.f, 0.f, 0.f, 0.f};
  #pragma unroll
  for (int kk = 0; kk < 4; ++kk) {
    int kbase = kk * 32 + kg * 8;
    f16x8 afr = *(f16x8*)&xs[(wv * 16 + row16) * LDH + kbase];
    #pragma unroll
    for (int j = 0; j < 4; ++j) {
      f16x8 bfr = *(f16x8*)&wt[(j * 16 + row16) * LDH + kbase];
      acc[j] = __builtin_amdgcn_mfma_f32_16x16x32_f16(afr, bfr, acc[j], 0, 0, 0);
    }
  }
  __syncthreads();
  #pragma unroll
  for (int j = 0; j < 4; ++j) {
    int col = j * 16 + row16;
    #pragma unroll
    for (int r = 0; r < 4; ++r) {
      int row = wv * 16 + kg * 4 + r;
      xs[row * LDH + col] = (_Float16)acc[j][r];
    }
  }
  __syncthreads();
  for (int i = t; i < 512; i += 256) {
    int r = i >> 3, c8 = i & 7;
    int n = n0 + r;
    if (n < N)
      __builtin_nontemporal_store(*(u32x4*)&xs[r * LDH + c8 * 8],
                                  &((u32x4*)Hh)[(size_t)n * 8 + c8]);
  }
  {
    int r = t >> 2, q = t & 3;
    int n = n0 + r;
    float ps = 0.f, pd = 0.f;
    #pragma unroll
    for (int qq = 0; qq < 2; ++qq) {
      f16x8 hv = *(f16x8*)&xs[r * LDH + q * 16 + qq * 8];
      float4 s0 = *(const float4*)&aw_s[q * 16 + qq * 8];
      float4 s1 = *(const float4*)&aw_s[q * 16 + qq * 8 + 4];
      float4 d0 = *(const float4*)&aw_d[q * 16 + qq * 8];
      float4 d1 = *(const float4*)&aw_d[q * 16 + qq * 8 + 4];
      ps += (float)hv[0] * s0.x + (float)hv[1] * s0.y + (float)hv[2] * s0.z + (float)hv[3] * s0.w
          + (float)hv[4] * s1.x + (float)hv[5] * s1.y + (float)hv[6] * s1.z + (float)hv[7] * s1.w;
      pd += (float)hv[0] * d0.x + (float)hv[1] * d0.y + (float)hv[2] * d0.z + (float)hv[3] * d0.w
          + (float)hv[4] * d1.x + (float)hv[5] * d1.y + (float)hv[6] * d1.z + (float)hv[7] * d1.w;
    }
    ps += __shfl_xor(ps, 1); ps += __shfl_xor(ps, 2);
    pd += __shfl_xor(pd, 1); pd += __shfl_xor(pd, 2);
    if (q == 0 && n < N) { as[n] = ps; ad[n] = pd; }
  }
}

__device__ __forceinline__ void load8h(const __half* p, float* f) {
  uint4 hv = *(const uint4*)p;
  float2 f0 = __half22float2(*(const __half2*)&hv.x);
  float2 f1 = __half22float2(*(const __half2*)&hv.y);
  float2 f2 = __half22float2(*(const __half2*)&hv.z);
  float2 f3 = __half22float2(*(const __half2*)&hv.w);
  f[0] = f0.x; f[1] = f0.y; f[2] = f1.x; f[3] = f1.y;
  f[4] = f2.x; f[5] = f2.y; f[6] = f3.x; f[7] = f3.y;
}

// ---------------- layer-1 merged aggregation (out fp16) ----------------
__global__ __launch_bounds__(256) void agg1_k(const int* __restrict__ rowptr,
                                              const int* __restrict__ srcs,
                                              const float* __restrict__ as,
                                              const float* __restrict__ ad,
                                              const __half* __restrict__ Hm,
                                              const float* __restrict__ bias,
                                              __half* __restrict__ out,
                                              const int* __restrict__ small_list,
                                              const int* __restrict__ big_list,
                                              const int* __restrict__ lcnt, int SB) {
  if (blockIdx.x < (unsigned)SB) {
    // ---- small role: node per 16-lane group ----
    __shared__ float al_sm[16][17][4];
    __shared__ int   sr_sm[16][16];
    int g  = threadIdx.x >> 4;
    int gl = threadIdx.x & 15;
    int gidx = blockIdx.x * 16 + g;
    if (gidx >= lcnt[0]) return;
    int n = small_list[gidx];
    int r0 = rowptr[n];
    int deg = rowptr[n + 1] - r0;
    float4 adn = *(const float4*)&ad[n * 4];

    float e0 = -INFINITY, e1 = -INFINITY, e2 = -INFINITY, e3 = -INFINITY;
    int s = 0;
    if (gl < deg) {
      s = __builtin_nontemporal_load(&srcs[r0 + gl]);
      float4 av = *(const float4*)&as[s * 4];
      e0 = leaky(av.x + adn.x); e1 = leaky(av.y + adn.y);
      e2 = leaky(av.z + adn.z); e3 = leaky(av.w + adn.w);
    }
    sr_sm[g][gl] = s;
    float m0 = e0, m1 = e1, m2 = e2, m3 = e3;
    #pragma unroll
    for (int off = 8; off > 0; off >>= 1) {
      m0 = fmaxf(m0, __shfl_xor(m0, off, 16)); m1 = fmaxf(m1, __shfl_xor(m1, off, 16));
      m2 = fmaxf(m2, __shfl_xor(m2, off, 16)); m3 = fmaxf(m3, __shfl_xor(m3, off, 16));
    }
    float sc0 = (gl < deg) ? __expf(e0 - m0) : 0.f;
    float sc1 = (gl < deg) ? __expf(e1 - m1) : 0.f;
    float sc2 = (gl < deg) ? __expf(e2 - m2) : 0.f;
    float sc3 = (gl < deg) ? __expf(e3 - m3) : 0.f;
    float s0 = sc0, s1 = sc1, s2 = sc2, s3 = sc3;
    #pragma unroll
    for (int off = 8; off > 0; off >>= 1) {
      s0 += __shfl_xor(s0, off, 16); s1 += __shfl_xor(s1, off, 16);
      s2 += __shfl_xor(s2, off, 16); s3 += __shfl_xor(s3, off, 16);
    }
    *(float4*)&al_sm[g][gl][0] =
        make_float4(sc0 / s0, sc1 / s1, sc2 / s2, sc3 / s3);

    int h = gl >> 2;
    int cbase = gl * 8;
    float a0 = 0.f, a1 = 0.f, a2 = 0.f, a3 = 0.f,
          a4 = 0.f, a5 = 0.f, a6 = 0.f, a7 = 0.f;
    for (int j = 0; j < deg; j += 8) {
      #pragma unroll
      for (int u = 0; u < 8; ++u) {
        int idx = j + u;
        bool vU = idx < deg;
        int jj = vU ? idx : 0;
        int   sU  = sr_sm[g][jj];
        float alU = vU ? al_sm[g][jj][h] : 0.f;
        float f[8];
        load8h(&Hm[(size_t)sU * 128 + cbase], f);
        a0 += f[0] * alU; a1 += f[1] * alU; a2 += f[2] * alU; a3 += f[3] * alU;
        a4 += f[4] * alU; a5 += f[5] * alU; a6 += f[6] * alU; a7 += f[7] * alU;
      }
    }
    float4 b0 = *(const float4*)&bias[cbase];
    float4 b1 = *(const float4*)&bias[cbase + 4];
    union { __half2 h2[4]; u32x4 u; } ov;
    ov.h2[0] = __floats2half2_rn(fmaxf(a0 + b0.x, 0.f), fmaxf(a1 + b0.y, 0.f));
    ov.h2[1] = __floats2half2_rn(fmaxf(a2 + b0.z, 0.f), fmaxf(a3 + b0.w, 0.f));
    ov.h2[2] = __floats2half2_rn(fmaxf(a4 + b1.x, 0.f), fmaxf(a5 + b1.y, 0.f));
    ov.h2[3] = __floats2half2_rn(fmaxf(a6 + b1.z, 0.f), fmaxf(a7 + b1.w, 0.f));
    __builtin_nontemporal_store(ov.u, (u32x4*)&out[(size_t)n * 128 + cbase]);
    return;
  }
  // ---- big role: node per wave ----
  __shared__ float al_sm[4][64][4];
  __shared__ int   sr_sm[4][64];
  int wv = threadIdx.x >> 6, lane = threadIdx.x & 63;
  int widx = (blockIdx.x - SB) * 4 + wv;
  if (widx >= lcnt[16]) return;
  int n = big_list[widx];
  int r0 = rowptr[n], r1 = rowptr[n + 1];
  int deg = r1 - r0;
  int grp = lane >> 4, gl = lane & 15, h = gl >> 2;
  int cbase = gl * 8;
  float4 adn = *(const float4*)&ad[n * 4];

  float a0 = 0.f, a1 = 0.f, a2 = 0.f, a3 = 0.f,
        a4 = 0.f, a5 = 0.f, a6 = 0.f, a7 = 0.f;

  if (deg <= 64) {
    float e0 = -INFINITY, e1 = -INFINITY, e2 = -INFINITY, e3 = -INFINITY;
    int s = 0;
    if (lane < deg) {
      s = __builtin_nontemporal_load(&srcs[r0 + lane]);
      float4 av = *(const float4*)&as[s * 4];
      e0 = leaky(av.x + adn.x); e1 = leaky(av.y + adn.y);
      e2 = leaky(av.z + adn.z); e3 = leaky(av.w + adn.w);
    }
    sr_sm[wv][lane] = s;
    float m0 = e0, m1 = e1, m2 = e2, m3 = e3;
    #pragma unroll
    for (int off = 32; off > 0; off >>= 1) {
      m0 = fmaxf(m0, __shfl_xor(m0, off)); m1 = fmaxf(m1, __shfl_xor(m1, off));
      m2 = fmaxf(m2, __shfl_xor(m2, off)); m3 = fmaxf(m3, __shfl_xor(m3, off));
    }
    float sc0 = (lane < deg) ? __expf(e0 - m0) : 0.f;
    float sc1 = (lane < deg) ? __expf(e1 - m1) : 0.f;
    float sc2 = (lane < deg) ? __expf(e2 - m2) : 0.f;
    float sc3 = (lane < deg) ? __expf(e3 - m3) : 0.f;
    float s0 = sc0, s1 = sc1, s2 = sc2, s3 = sc3;
    #pragma unroll
    for (int off = 32; off > 0; off >>= 1) {
      s0 += __shfl_xor(s0, off); s1 += __shfl_xor(s1, off);
      s2 += __shfl_xor(s2, off); s3 += __shfl_xor(s3, off);
    }
    *(float4*)&al_sm[wv][lane][0] =
        make_float4(sc0 / s0, sc1 / s1, sc2 / s2, sc3 / s3);

    for (int base = 0; base < deg; base += 16) {
      #pragma unroll
      for (int u = 0; u < 4; ++u) {
        int idx = base + grp * 4 + u;
        bool vU = idx < deg;
        int jj = vU ? idx : 0;
        int   sU  = sr_sm[wv][jj];
        float alU = vU ? al_sm[wv][jj][h] : 0.f;
        float f[8];
        load8h(&Hm[(size_t)sU * 128 + cbase], f);
        a0 += f[0] * alU; a1 += f[1] * alU; a2 += f[2] * alU; a3 += f[3] * alU;
        a4 += f[4] * alU; a5 += f[5] * alU; a6 += f[6] * alU; a7 += f[7] * alU;
      }
    }
  } else {
    float m0 = -INFINITY, m1 = -INFINITY, m2 = -INFINITY, m3 = -INFINITY;
    for (int r = r0 + lane; r < r1; r += 64) {
      int s = srcs[r];
      float4 av = *(const float4*)&as[s * 4];
      m0 = fmaxf(m0, leaky(av.x + adn.x)); m1 = fmaxf(m1, leaky(av.y + adn.y));
      m2 = fmaxf(m2, leaky(av.z + adn.z)); m3 = fmaxf(m3, leaky(av.w + adn.w));
    }
    #pragma unroll
    for (int off = 32; off > 0; off >>= 1) {
      m0 = fmaxf(m0, __shfl_xor(m0, off)); m1 = fmaxf(m1, __shfl_xor(m1, off));
      m2 = fmaxf(m2, __shfl_xor(m2, off)); m3 = fmaxf(m3, __shfl_xor(m3, off));
    }
    float s0 = 0.f, s1 = 0.f, s2 = 0.f, s3 = 0.f;
    for (int r = r0 + lane; r < r1; r += 64) {
      int s = srcs[r];
      float4 av = *(const float4*)&as[s * 4];
      s0 += __expf(leaky(av.x + adn.x) - m0); s1 += __expf(leaky(av.y + adn.y) - m1);
      s2 += __expf(leaky(av.z + adn.z) - m2); s3 += __expf(leaky(av.w + adn.w) - m3);
    }
    #pragma unroll
    for (int off = 32; off > 0; off >>= 1) {
      s0 += __shfl_xor(s0, off); s1 += __shfl_xor(s1, off);
      s2 += __shfl_xor(s2, off); s3 += __shfl_xor(s3, off);
    }
    float mhh = (h == 0) ? m0 : (h == 1) ? m1 : (h == 2) ? m2 : m3;
    float inv = 1.f / ((h == 0) ? s0 : (h == 1) ? s1 : (h == 2) ? s2 : s3);
    float adh = (h == 0) ? adn.x : (h == 1) ? adn.y : (h == 2) ? adn.z : adn.w;
    for (int r = r0; r < r1; r += 8) {
      int rA = r + grp, rB = rA + 4;
      bool vA = rA < r1, vB = rB < r1;
      int sA = srcs[vA ? rA : r0];
      int sB = srcs[vB ? rB : r0];
      float avA = as[sA * 4 + h], avB = as[sB * 4 + h];
      float alA = vA ? (__expf(leaky(avA + adh) - mhh) * inv) : 0.f;
      float alB = vB ? (__expf(leaky(avB + adh) - mhh) * inv) : 0.f;
      float fA[8], fB[8];
      load8h(&Hm[(size_t)sA * 128 + cbase], fA);
      load8h(&Hm[(size_t)sB * 128 + cbase], fB);
      a0 += fA[0] * alA + fB[0] * alB; a1 += fA[1] * alA + fB[1] * alB;
      a2 += fA[2] * alA + fB[2] * alB; a3 += fA[3] * alA + fB[3] * alB;
      a4 += fA[4] * alA + fB[4] * alB; a5 += fA[5] * alA + fB[5] * alB;
      a6 += fA[6] * alA + fB[6] * alB; a7 += fA[7] * alA + fB[7] * alB;
    }
  }
  a0 += __shfl_xor(a0, 16); a0 += __shfl_xor(a0, 32);
  a1 += __shfl_xor(a1, 16); a1 += __shfl_xor(a1, 32);
  a2 += __shfl_xor(a2, 16); a2 += __shfl_xor(a2, 32);
  a3 += __shfl_xor(a3, 16); a3 += __shfl_xor(a3, 32);
  a4 += __shfl_xor(a4, 16); a4 += __shfl_xor(a4, 32);
  a5 += __shfl_xor(a5, 16); a5 += __shfl_xor(a5, 32);
  a6 += __shfl_xor(a6, 16); a6 += __shfl_xor(a6, 32);
  a7 += __shfl_xor(a7, 16); a7 += __shfl_xor(a7, 32);
  if (grp == 0) {
    float4 b0 = *(const float4*)&bias[cbase];
    float4 b1 = *(const float4*)&bias[cbase + 4];
    union { __half2 h2[4]; u32x4 u; } ov;
    ov.h2[0] = __floats2half2_rn(fmaxf(a0 + b0.x, 0.f), fmaxf(a1 + b0.y, 0.f));
    ov.h2[1] = __floats2half2_rn(fmaxf(a2 + b0.z, 0.f), fmaxf(a3 + b0.w, 0.f));
    ov.h2[2] = __floats2half2_rn(fmaxf(a4 + b1.x, 0.f), fmaxf(a5 + b1.y, 0.f));
    ov.h2[3] = __floats2half2_rn(fmaxf(a6 + b1.z, 0.f), fmaxf(a7 + b1.w, 0.f));
    __builtin_nontemporal_store(ov.u, (u32x4*)&out[(size_t)n * 128 + cbase]);
  }
}

// ---------------- layer-2 merged aggregation (out fp32 = d_out) ----------------
__global__ __launch_bounds__(256) void agg2_k(const int* __restrict__ rowptr,
                                              const int* __restrict__ srcs,
                                              const float* __restrict__ as,
                                              const float* __restrict__ ad,
                                              const __half* __restrict__ Hm,
                                              const float* __restrict__ bias,
                                              float* __restrict__ out,
                                              const int* __restrict__ small_list,
                                              const int* __restrict__ big_list,
                                              const int* __restrict__ lcnt, int SB) {
  if (blockIdx.x < (unsigned)SB) {
    __shared__ float al_sm[16][17];
    __shared__ int   sr_sm[16][16];
    int g  = threadIdx.x >> 4;
    int gl = threadIdx.x & 15;
    int gidx = blockIdx.x * 16 + g;
    if (gidx >= lcnt[0]) return;
    int n = small_list[gidx];
    int r0 = rowptr[n];
    int deg = rowptr[n + 1] - r0;
    float adn = ad[n];

    float e = -INFINITY;
    int s = 0;
    if (gl < deg) { s = __builtin_nontemporal_load(&srcs[r0 + gl]); e = leaky(as[s] + adn); }
    sr_sm[g][gl] = s;
    float m = e;
    #pragma unroll
    for (int off = 8; off > 0; off >>= 1) m = fmaxf(m, __shfl_xor(m, off, 16));
    float sc = (gl < deg) ? __expf(e - m) : 0.f;
    float ssum = sc;
    #pragma unroll
    for (int off = 8; off > 0; off >>= 1) ssum += __shfl_xor(ssum, off, 16);
    al_sm[g][gl] = sc / ssum;

    int cbase = gl * 4;
    float a0 = 0.f, a1 = 0.f, a2 = 0.f, a3 = 0.f;
    for (int j = 0; j < deg; j += 8) {
      #pragma unroll
      for (int u = 0; u < 8; ++u) {
        int idx = j + u;
        bool vU = idx < deg;
        int jj = vU ? idx : 0;
        int   sU  = sr_sm[g][jj];
        float alU = vU ? al_sm[g][jj] : 0.f;
        uint2 hv = *(const uint2*)&Hm[(size_t)sU * 64 + cbase];
        float2 f0 = __half22float2(*(const __half2*)&hv.x);
        float2 f1 = __half22float2(*(const __half2*)&hv.y);
        a0 += f0.x * alU; a1 += f0.y * alU; a2 += f1.x * alU; a3 += f1.y * alU;
      }
    }
    float4 bv = *(const float4*)&bias[cbase];
    f32x4 o;
    o[0] = a0 + bv.x; o[1] = a1 + bv.y; o[2] = a2 + bv.z; o[3] = a3 + bv.w;
    __builtin_nontemporal_store(o, (f32x4*)&out[(size_t)n * 64 + cbase]);
    return;
  }
  __shared__ float al_sm[4][64];
  __shared__ int   sr_sm[4][64];
  int wv = threadIdx.x >> 6, lane = threadIdx.x & 63;
  int widx = (blockIdx.x - SB) * 4 + wv;
  if (widx >= lcnt[16]) return;
  int n = big_list[widx];
  int r0 = rowptr[n], r1 = rowptr[n + 1];
  int deg = r1 - r0;
  int grp = lane >> 4, gl = lane & 15;
  int cbase = gl * 4;
  float adn = ad[n];

  float a0 = 0.f, a1 = 0.f, a2 = 0.f, a3 = 0.f;

  if (deg <= 64) {
    float e = -INFINITY;
    int s = 0;
    if (lane < deg) { s = __builtin_nontemporal_load(&srcs[r0 + lane]); e = leaky(as[s] + adn); }
    sr_sm[wv][lane] = s;
    float m = e;
    #pragma unroll
    for (int off = 32; off > 0; off >>= 1) m = fmaxf(m, __shfl_xor(m, off));
    float sc = (lane < deg) ? __expf(e - m) : 0.f;
    float ssum = sc;
    #pragma unroll
    for (int off = 32; off > 0; off >>= 1) ssum += __shfl_xor(ssum, off);
    al_sm[wv][lane] = sc / ssum;

    for (int base = 0; base < deg; base += 16) {
      #pragma unroll
      for (int u = 0; u < 4; ++u) {
        int idx = base + grp * 4 + u;
        bool vU = idx < deg;
        int jj = vU ? idx : 0;
        int   sU  = sr_sm[wv][jj];
        float alU = vU ? al_sm[wv][jj] : 0.f;
        uint2 hv = *(const uint2*)&Hm[(size_t)sU * 64 + cbase];
        float2 f0 = __half22float2(*(const __half2*)&hv.x);
        float2 f1 = __half22float2(*(const __half2*)&hv.y);
        a0 += f0.x * alU; a1 += f0.y * alU; a2 += f1.x * alU; a3 += f1.y * alU;
      }
    }
  } else {
    float mh = -INFINITY;
    for (int r = r0 + lane; r < r1; r += 64)
      mh = fmaxf(mh, leaky(as[srcs[r]] + adn));
    #pragma unroll
    for (int off = 32; off > 0; off >>= 1) mh = fmaxf(mh, __shfl_xor(mh, off));
    float ssum = 0.f;
    for (int r = r0 + lane; r < r1; r += 64)
      ssum += __expf(leaky(as[srcs[r]] + adn) - mh);
    #pragma unroll
    for (int off = 32; off > 0; off >>= 1) ssum += __shfl_xor(ssum, off);
    float inv = 1.f / ssum;
    for (int r = r0; r < r1; r += 8) {
      int rA = r + grp, rB = rA + 4;
      bool vA = rA < r1, vB = rB < r1;
      int sA = srcs[vA ? rA : r0];
      int sB = srcs[vB ? rB : r0];
      float alA = vA ? (__expf(leaky(as[sA] + adn) - mh) * inv) : 0.f;
      float alB = vB ? (__expf(leaky(as[sB] + adn) - mh) * inv) : 0.f;
      uint2 hvA = *(const uint2*)&Hm[(size_t)sA * 64 + cbase];
      uint2 hvB = *(const uint2*)&Hm[(size_t)sB * 64 + cbase];
      float2 fA0 = __half22float2(*(const __half2*)&hvA.x);
      float2 fA1 = __half22float2(*(const __half2*)&hvA.y);
      float2 fB0 = __half22float2(*(const __half2*)&hvB.x);
      float2 fB1 = __half22float2(*(const __half2*)&hvB.y);
      a0 += fA0.x * alA + fB0.x * alB; a1 += fA0.y * alA + fB0.y * alB;
      a2 += fA1.x * alA + fB1.x * alB; a3 += fA1.y * alA + fB1.y * alB;
    }
  }
  a0 += __shfl_xor(a0, 16); a0 += __shfl_xor(a0, 32);
  a1 += __shfl_xor(a1, 16); a1 += __shfl_xor(a1, 32);
  a2 += __shfl_xor(a2, 16); a2 += __shfl_xor(a2, 32);
  a3 += __shfl_xor(a3, 16); a3 += __shfl_xor(a3, 32);
  if (grp == 0) {
    float4 bv = *(const float4*)&bias[cbase];
    f32x4 o;
    o[0] = a0 + bv.x; o[1] = a1 + bv.y; o[2] = a2 + bv.z; o[3] = a3 + bv.w;
    __builtin_nontemporal_store(o, (f32x4*)&out[(size_t)n * 64 + cbase]);
  }
}

extern "C" void kernel_launch(void* const* d_in, const int* in_sizes, int n_in,
                              void* d_out, int out_size, void* d_ws, size_t ws_size,
                              hipStream_t stream) {
  const float* x   = (const float*)d_in[0];
  const int*   ei  = (const int*)d_in[1];
  // d_in[2] edge_weight: unused by GATConv (edge_dim unset)
  const float* W1  = (const float*)d_in[3];
  const float* aS1 = (const float*)d_in[4];
  const float* aD1 = (const float*)d_in[5];
  const float* b1  = (const float*)d_in[6];
  const float* W2  = (const float*)d_in[7];
  const float* aS2 = (const float*)d_in[8];
  const float* aD2 = (const float*)d_in[9];
  const float* b2  = (const float*)d_in[10];

  const int N  = in_sizes[0] / 128;
  const int E  = in_sizes[2];
  const int ET = E + N;
  const int NB = (N + 127) >> 7;

  float* ws    = (float*)d_ws;
  __half* h1h  = (__half*)ws;                  // N*128 halfs
  __half* o1h  = (__half*)(ws + (size_t)N * 64);  // N*128 halfs (out1, fp16)
  float* as1   = ws + (size_t)N * 128;         // 4N
  float* ad1   = as1  + (size_t)4 * N;         // 4N
  float* as2   = ad1  + (size_t)4 * N;         // N
  float* ad2   = as2  + (size_t)N;             // N
  int*   lcnt    = (int*)(ad2 + (size_t)N);    // 32
  int*   rowptr  = lcnt + 32;                  // N+1
  int*   bbase   = rowptr + N + 1;             // NB+1
  int*   blkpref = bbase + NB + 1;             // NB*NBLKA
  int*   small_list = blkpref + NB * NBLKA;    // N
  int*   big_list   = small_list + N;          // N
  int*   srcs   = big_list + N;                // ET
  _Float16* w1t = (_Float16*)(srcs + ET);      // 128*128 halfs
  _Float16* w2t = w1t + 128 * 128;             // 64*128 halfs
  int*   pairs  = (int*)ws;                    // ET ints, aliased onto h1h
  __half* h2h  = h1h;                          // alias (h1h dead after agg1)
  float* out  = (float*)d_out;                 // N*64

  const int gb = (N + 63) / 64;
  const int sb = (N + 15) / 16;
  const int bb = (N + 3) / 4;

  // ---- CSR build (+ W transpose in histc block 0) ----
  histc_k<<<NBLKA, 256, 0, stream>>>(ei, E, ET, blkpref, NB, W1, W2, w1t, w2t, lcnt);
  scan_blk_k<<<NB, 256, 0, stream>>>(blkpref, bbase, lcnt, rowptr, NB, N, ET);
  passA_k<<<NBLKA, 256, 0, stream>>>(ei, E, ET, bbase, blkpref, pairs, NB);
  passB_k<<<NB, 256, 0, stream>>>(pairs, bbase, rowptr, srcs,
                                  small_list, big_list, lcnt, N);

  // ---- layer 1 ----
  gemm1_k<<<gb, 256, 0, stream>>>(x, w1t, aS1, aD1, h1h, as1, ad1, N);
  agg1_k<<<sb + bb, 256, 0, stream>>>(rowptr, srcs, as1, ad1, h1h, b1, o1h,
                                      small_list, big_list, lcnt, sb);

  // ---- layer 2 ----
  gemm2_k<<<gb, 256, 0, stream>>>(o1h, w2t, aS2, aD2, h2h, as2, ad2, N);
  agg2_k<<<sb + bb, 256, 0, stream>>>(rowptr, srcs, as2, ad2, h2h, b2, out,
                                      small_list, big_list, lcnt, sb);
}

// Round 5
// 246.335 us; speedup vs baseline: 1.0474x; 1.0474x over previous
//
#include <hip/hip_runtime.h>
#include <hip/hip_fp16.h>
#include <math.h>

// GAT (2 layers) on MI355X — radix CSR + merged degree-bucketed aggregation.
// R1: gemm1/gemm2 MFMA (16x16x32 f16, fp32 accum).
// R4: NT ops ONLY on single-use data (X load, final out store) — R2's NT on
//     gather tables (h1h/h2h) bypassed cache and cost +42us. Fused scan kept.

#define NEG_SLOPE 0.2f
#define NBLKA 256
#define MAXNB 512
#define LDH 136   // padded halfs per LDS row

typedef _Float16 f16x8 __attribute__((ext_vector_type(8)));
typedef float f32x4 __attribute__((ext_vector_type(4)));
typedef unsigned int u32x4 __attribute__((ext_vector_type(4)));

__device__ __forceinline__ float leaky(float v) { return v > 0.f ? v : NEG_SLOPE * v; }

// ---------------- CSR build: radix partition by dst (+ W transpose prep) ----------------
__global__ __launch_bounds__(256) void histc_k(const int* __restrict__ ei, int E, int ET,
                                               int* __restrict__ blkpref, int NB,
                                               const float* __restrict__ W1,
                                               const float* __restrict__ W2,
                                               _Float16* __restrict__ w1t,
                                               _Float16* __restrict__ w2t,
                                               int* __restrict__ lcnt) {
  __shared__ int lhist[MAXNB];
  int chunk = (ET + NBLKA - 1) / NBLKA;
  int e0 = blockIdx.x * chunk, e1 = min(ET, e0 + chunk);
  for (int b = threadIdx.x; b < NB; b += 256) lhist[b] = 0;
  __syncthreads();
  for (int e = e0 + threadIdx.x; e < e1; e += 256) {
    int d = (e < E) ? ei[E + e] : (e - E);
    atomicAdd(&lhist[d >> 7], 1);
  }
  __syncthreads();
  for (int b = threadIdx.x; b < NB; b += 256)
    blkpref[b * NBLKA + blockIdx.x] = lhist[b];
  // W1T [128n][128k], W2T [64n][128k] fp16 — block 0 only; also init last-block counter
  if (blockIdx.x == 0) {
    int t = threadIdx.x;
    if (t == 255) lcnt[31] = 0;
    if (t < 128) {
      union { _Float16 h[8]; u32x4 u; } buf;
      for (int k0 = 0; k0 < 128; k0 += 8) {
        #pragma unroll
        for (int u = 0; u < 8; ++u) buf.h[u] = (_Float16)W1[(k0 + u) * 128 + t];
        *(u32x4*)&w1t[t * 128 + k0] = buf.u;
      }
    } else if (t < 192) {
      int n = t - 128;
      union { _Float16 h[8]; u32x4 u; } buf;
      for (int k0 = 0; k0 < 128; k0 += 8) {
        #pragma unroll
        for (int u = 0; u < 8; ++u) buf.h[u] = (_Float16)W2[(k0 + u) * 64 + n];
        *(u32x4*)&w2t[n * 128 + k0] = buf.u;
      }
    }
  }
}

// scan within each bucket-row, then last block scans bucket bases (folded scan_bkt)
__global__ __launch_bounds__(256) void scan_blk_k(int* __restrict__ blkpref,
                                                  int* __restrict__ bbase,
                                                  int* __restrict__ lcnt,
                                                  int* __restrict__ rowptr,
                                                  int NB, int N, int ET) {
  __shared__ int sm[NBLKA];
  __shared__ int lastflag;
  int b = blockIdx.x, t = threadIdx.x;
  int v = blkpref[b * NBLKA + t];
  sm[t] = v;
  __syncthreads();
  #pragma unroll
  for (int off = 1; off < NBLKA; off <<= 1) {
    int x = (t >= off) ? sm[t - off] : 0;
    __syncthreads();
    sm[t] += x;
    __syncthreads();
  }
  blkpref[b * NBLKA + t] = sm[t] - v;
  if (t == NBLKA - 1) bbase[b] = sm[t];
  __threadfence();
  if (t == 0) lastflag = atomicAdd(&lcnt[31], 1);
  __syncthreads();
  if (lastflag != (int)gridDim.x - 1) return;
  // ---- last block: exclusive scan of bbase[0..NB-1] -> bbase[0..NB] ----
  int i0 = 2 * t, i1 = 2 * t + 1;
  int a = (i0 < NB) ? atomicAdd(&bbase[i0], 0) : 0;
  int c = (i1 < NB) ? atomicAdd(&bbase[i1], 0) : 0;
  __syncthreads();
  sm[t] = a + c;
  __syncthreads();
  #pragma unroll
  for (int off = 1; off < 256; off <<= 1) {
    int x = (t >= off) ? sm[t - off] : 0;
    __syncthreads();
    sm[t] += x;
    __syncthreads();
  }
  int base = sm[t] - (a + c);
  if (i0 <= NB) bbase[i0] = base;
  if (i1 <= NB) bbase[i1] = base + a;
  if (t == 0) { lcnt[0] = 0; lcnt[16] = 0; rowptr[N] = ET; }
}

__global__ __launch_bounds__(256) void passA_k(const int* __restrict__ ei, int E, int ET,
                                               const int* __restrict__ bbase,
                                               const int* __restrict__ blkpref,
                                               int* __restrict__ pairs, int NB) {
  __shared__ int lcur[MAXNB];
  int chunk = (ET + NBLKA - 1) / NBLKA;
  int e0 = blockIdx.x * chunk, e1 = min(ET, e0 + chunk);
  for (int b = threadIdx.x; b < NB; b += 256)
    lcur[b] = bbase[b] + blkpref[b * NBLKA + blockIdx.x];
  __syncthreads();
  for (int e = e0 + threadIdx.x; e < e1; e += 256) {
    int s, d;
    if (e < E) { s = ei[e]; d = ei[E + e]; } else { s = d = e - E; }
    int b = d >> 7;
    int pos = atomicAdd(&lcur[b], 1);
    pairs[pos] = ((d & 127) << 17) | s;
  }
}

__global__ __launch_bounds__(256) void passB_k(const int* __restrict__ pairs,
                                               const int* __restrict__ bbase,
                                               int* __restrict__ rowptr,
                                               int* __restrict__ srcs,
                                               int* __restrict__ small_list,
                                               int* __restrict__ big_list,
                                               int* __restrict__ lcnt, int N) {
  __shared__ int ncnt[128], spre[128], lcur[128];
  __shared__ int wcS[2], wcB[2], bS, bB;
  int b = blockIdx.x, t = threadIdx.x;
  int nb0 = b << 7;
  int nn = min(128, N - nb0);
  int e0 = bbase[b], e1 = bbase[b + 1];
  if (t < 128) ncnt[t] = 0;
  __syncthreads();
  for (int r = e0 + t; r < e1; r += 256)
    atomicAdd(&ncnt[pairs[r] >> 17], 1);
  __syncthreads();
  if (t < 128) spre[t] = ncnt[t];
  __syncthreads();
  #pragma unroll
  for (int off = 1; off < 128; off <<= 1) {
    int x = (t < 128 && t >= off) ? spre[t - off] : 0;
    __syncthreads();
    if (t < 128) spre[t] += x;
    __syncthreads();
  }
  if (t < nn) {
    int base = e0 + spre[t] - ncnt[t];
    rowptr[nb0 + t] = base;
    lcur[t] = base;
  }
  __syncthreads();
  for (int r = e0 + t; r < e1; r += 256) {
    int p = pairs[r];
    int pos = atomicAdd(&lcur[p >> 17], 1);
    srcs[pos] = p & 0x1FFFF;
  }
  int lane = t & 63, wv = t >> 6;
  bool valid = (t < nn);
  int deg = valid ? ncnt[t] : 0;
  bool isS = valid && (deg <= 16);
  bool isB = valid && (deg > 16);
  unsigned long long ms = __ballot(isS);
  unsigned long long mb = __ballot(isB);
  if (lane == 0 && wv < 2) { wcS[wv] = __popcll(ms); wcB[wv] = __popcll(mb); }
  __syncthreads();
  if (t == 0) {
    bS = atomicAdd(&lcnt[0],  wcS[0] + wcS[1]);
    bB = atomicAdd(&lcnt[16], wcB[0] + wcB[1]);
  }
  __syncthreads();
  unsigned long long below = (lane == 0) ? 0ull : (~0ull >> (64 - lane));
  int offS = bS + ((wv == 1) ? wcS[0] : 0);
  int offB = bB + ((wv == 1) ? wcB[0] : 0);
  if (isS) small_list[offS + __popcll(ms & below)] = nb0 + t;
  if (isB) big_list[offB + __popcll(mb & below)]   = nb0 + t;
}

// ---------------- GEMM1 (MFMA) + alpha1: h1h = X(fp32) @ W1 ----------------
__global__ __launch_bounds__(256) void gemm1_k(const float* __restrict__ X,
                                               const _Float16* __restrict__ WT,
                                               const float* __restrict__ aw_s,
                                               const float* __restrict__ aw_d,
                                               __half* __restrict__ Hh,
                                               float* __restrict__ as,
                                               float* __restrict__ ad, int N) {
  __shared__ _Float16 xs[64 * LDH];    // X tile fp16 (also epilogue buffer)
  __shared__ _Float16 wt[128 * LDH];   // W1T tile [n][k]
  int t = threadIdx.x;
  int n0 = blockIdx.x * 64;
  for (int i = t; i < 2048; i += 256) {
    int r = i >> 4, c8 = i & 15;
    *(u32x4*)&wt[r * LDH + c8 * 8] = ((const u32x4*)WT)[i];
  }
  for (int i = t; i < 2048; i += 256) {
    int r = i >> 5, c4 = i & 31;
    int n = n0 + r;
    f32x4 xv = (n < N) ? __builtin_nontemporal_load(&((const f32x4*)X)[(size_t)n * 32 + c4])
                       : (f32x4){0.f, 0.f, 0.f, 0.f};
    __half2 h0 = __floats2half2_rn(xv[0], xv[1]);
    __half2 h1 = __floats2half2_rn(xv[2], xv[3]);
    uint2 u; u.x = *(unsigned*)&h0; u.y = *(unsigned*)&h1;
    *(uint2*)&xs[r * LDH + c4 * 4] = u;
  }
  __syncthreads();
  int wv = t >> 6, l = t & 63;
  int row16 = l & 15, kg = l >> 4;
  f32x4 acc[8];
  #pragma unroll
  for (int j = 0; j < 8; ++j) acc[j] = (f32x4){0.f, 0.f, 0.f, 0.f};
  #pragma unroll
  for (int kk = 0; kk < 4; ++kk) {
    int kbase = kk * 32 + kg * 8;
    f16x8 afr = *(f16x8*)&xs[(wv * 16 + row16) * LDH + kbase];
    #pragma unroll
    for (int j = 0; j < 8; ++j) {
      f16x8 bfr = *(f16x8*)&wt[(j * 16 + row16) * LDH + kbase];
      acc[j] = __builtin_amdgcn_mfma_f32_16x16x32_f16(afr, bfr, acc[j], 0, 0, 0);
    }
  }
  __syncthreads();
  #pragma unroll
  for (int j = 0; j < 8; ++j) {
    int col = j * 16 + row16;
    #pragma unroll
    for (int r = 0; r < 4; ++r) {
      int row = wv * 16 + kg * 4 + r;
      xs[row * LDH + col] = (_Float16)acc[j][r];
    }
  }
  __syncthreads();
  for (int i = t; i < 1024; i += 256) {
    int r = i >> 4, c8 = i & 15;
    int n = n0 + r;
    if (n < N) ((u32x4*)Hh)[(size_t)n * 16 + c8] = *(u32x4*)&xs[r * LDH + c8 * 8];
  }
  {
    int r = t >> 2, h = t & 3;
    int n = n0 + r;
    float ps = 0.f, pd = 0.f;
    #pragma unroll
    for (int q = 0; q < 4; ++q) {
      f16x8 hv = *(f16x8*)&xs[r * LDH + h * 32 + q * 8];
      float4 s0 = *(const float4*)&aw_s[h * 32 + q * 8];
      float4 s1 = *(const float4*)&aw_s[h * 32 + q * 8 + 4];
      float4 d0 = *(const float4*)&aw_d[h * 32 + q * 8];
      float4 d1 = *(const float4*)&aw_d[h * 32 + q * 8 + 4];
      ps += (float)hv[0] * s0.x + (float)hv[1] * s0.y + (float)hv[2] * s0.z + (float)hv[3] * s0.w
          + (float)hv[4] * s1.x + (float)hv[5] * s1.y + (float)hv[6] * s1.z + (float)hv[7] * s1.w;
      pd += (float)hv[0] * d0.x + (float)hv[1] * d0.y + (float)hv[2] * d0.z + (float)hv[3] * d0.w
          + (float)hv[4] * d1.x + (float)hv[5] * d1.y + (float)hv[6] * d1.z + (float)hv[7] * d1.w;
    }
    if (n < N) { as[n * 4 + h] = ps; ad[n * 4 + h] = pd; }
  }
}

// ---------------- GEMM2 (MFMA) + alpha2: h2h = o1h(fp16) @ W2 ----------------
__global__ __launch_bounds__(256) void gemm2_k(const __half* __restrict__ X,
                                               const _Float16* __restrict__ WT,
                                               const float* __restrict__ aw_s,
                                               const float* __restrict__ aw_d,
                                               __half* __restrict__ Hh,
                                               float* __restrict__ as,
                                               float* __restrict__ ad, int N) {
  __shared__ _Float16 xs[64 * LDH];
  __shared__ _Float16 wt[64 * LDH];
  int t = threadIdx.x;
  int n0 = blockIdx.x * 64;
  for (int i = t; i < 1024; i += 256) {
    int r = i >> 4, c8 = i & 15;
    *(u32x4*)&wt[r * LDH + c8 * 8] = ((const u32x4*)WT)[i];
  }
  for (int i = t; i < 1024; i += 256) {
    int r = i >> 4, c8 = i & 15;
    int n = n0 + r;
    u32x4 v = (n < N) ? ((const u32x4*)X)[(size_t)n * 16 + c8] : (u32x4){0, 0, 0, 0};
    *(u32x4*)&xs[r * LDH + c8 * 8] = v;
  }
  __syncthreads();
  int wv = t >> 6, l = t & 63;
  int row16 = l & 15, kg = l >> 4;
  f32x4 acc[4];
  #pragma unroll
  for (int j = 0; j < 4; ++j) acc[j] = (f32x4){0.f, 0.f, 0.f, 0.f};
  #pragma unroll
  for (int kk = 0; kk < 4; ++kk) {
    int kbase = kk * 32 + kg * 8;
    f16x8 afr = *(f16x8*)&xs[(wv * 16 + row16) * LDH + kbase];
    #pragma unroll
    for (int j = 0; j < 4; ++j) {
      f16x8 bfr = *(f16x8*)&wt[(j * 16 + row16) * LDH + kbase];
      acc[j] = __builtin_amdgcn_mfma_f32_16x16x32_f16(afr, bfr, acc[j], 0, 0, 0);
    }
  }
  __syncthreads();
  #pragma unroll
  for (int j = 0; j < 4; ++j) {
    int col = j * 16 + row16;
    #pragma unroll
    for (int r = 0; r < 4; ++r) {
      int row = wv * 16 + kg * 4 + r;
      xs[row * LDH + col] = (_Float16)acc[j][r];
    }
  }
  __syncthreads();
  for (int i = t; i < 512; i += 256) {
    int r = i >> 3, c8 = i & 7;
    int n = n0 + r;
    if (n < N) ((u32x4*)Hh)[(size_t)n * 8 + c8] = *(u32x4*)&xs[r * LDH + c8 * 8];
  }
  {
    int r = t >> 2, q = t & 3;
    int n = n0 + r;
    float ps = 0.f, pd = 0.f;
    #pragma unroll
    for (int qq = 0; qq < 2; ++qq) {
      f16x8 hv = *(f16x8*)&xs[r * LDH + q * 16 + qq * 8];
      float4 s0 = *(const float4*)&aw_s[q * 16 + qq * 8];
      float4 s1 = *(const float4*)&aw_s[q * 16 + qq * 8 + 4];
      float4 d0 = *(const float4*)&aw_d[q * 16 + qq * 8];
      float4 d1 = *(const float4*)&aw_d[q * 16 + qq * 8 + 4];
      ps += (float)hv[0] * s0.x + (float)hv[1] * s0.y + (float)hv[2] * s0.z + (float)hv[3] * s0.w
          + (float)hv[4] * s1.x + (float)hv[5] * s1.y + (float)hv[6] * s1.z + (float)hv[7] * s1.w;
      pd += (float)hv[0] * d0.x + (float)hv[1] * d0.y + (float)hv[2] * d0.z + (float)hv[3] * d0.w
          + (float)hv[4] * d1.x + (float)hv[5] * d1.y + (float)hv[6] * d1.z + (float)hv[7] * d1.w;
    }
    ps += __shfl_xor(ps, 1); ps += __shfl_xor(ps, 2);
    pd += __shfl_xor(pd, 1); pd += __shfl_xor(pd, 2);
    if (q == 0 && n < N) { as[n] = ps; ad[n] = pd; }
  }
}

__device__ __forceinline__ void load8h(const __half* p, float* f) {
  uint4 hv = *(const uint4*)p;
  float2 f0 = __half22float2(*(const __half2*)&hv.x);
  float2 f1 = __half22float2(*(const __half2*)&hv.y);
  float2 f2 = __half22float2(*(const __half2*)&hv.z);
  float2 f3 = __half22float2(*(const __half2*)&hv.w);
  f[0] = f0.x; f[1] = f0.y; f[2] = f1.x; f[3] = f1.y;
  f[4] = f2.x; f[5] = f2.y; f[6] = f3.x; f[7] = f3.y;
}

// ---------------- layer-1 merged aggregation (out fp16) ----------------
__global__ __launch_bounds__(256) void agg1_k(const int* __restrict__ rowptr,
                                              const int* __restrict__ srcs,
                                              const float* __restrict__ as,
                                              const float* __restrict__ ad,
                                              const __half* __restrict__ Hm,
                                              const float* __restrict__ bias,
                                              __half* __restrict__ out,
                                              const int* __restrict__ small_list,
                                              const int* __restrict__ big_list,
                                              const int* __restrict__ lcnt, int SB) {
  if (blockIdx.x < (unsigned)SB) {
    // ---- small role: node per 16-lane group ----
    __shared__ float al_sm[16][17][4];
    __shared__ int   sr_sm[16][16];
    int g  = threadIdx.x >> 4;
    int gl = threadIdx.x & 15;
    int gidx = blockIdx.x * 16 + g;
    if (gidx >= lcnt[0]) return;
    int n = small_list[gidx];
    int r0 = rowptr[n];
    int deg = rowptr[n + 1] - r0;
    float4 adn = *(const float4*)&ad[n * 4];

    float e0 = -INFINITY, e1 = -INFINITY, e2 = -INFINITY, e3 = -INFINITY;
    int s = 0;
    if (gl < deg) {
      s = srcs[r0 + gl];
      float4 av = *(const float4*)&as[s * 4];
      e0 = leaky(av.x + adn.x); e1 = leaky(av.y + adn.y);
      e2 = leaky(av.z + adn.z); e3 = leaky(av.w + adn.w);
    }
    sr_sm[g][gl] = s;
    float m0 = e0, m1 = e1, m2 = e2, m3 = e3;
    #pragma unroll
    for (int off = 8; off > 0; off >>= 1) {
      m0 = fmaxf(m0, __shfl_xor(m0, off, 16)); m1 = fmaxf(m1, __shfl_xor(m1, off, 16));
      m2 = fmaxf(m2, __shfl_xor(m2, off, 16)); m3 = fmaxf(m3, __shfl_xor(m3, off, 16));
    }
    float sc0 = (gl < deg) ? __expf(e0 - m0) : 0.f;
    float sc1 = (gl < deg) ? __expf(e1 - m1) : 0.f;
    float sc2 = (gl < deg) ? __expf(e2 - m2) : 0.f;
    float sc3 = (gl < deg) ? __expf(e3 - m3) : 0.f;
    float s0 = sc0, s1 = sc1, s2 = sc2, s3 = sc3;
    #pragma unroll
    for (int off = 8; off > 0; off >>= 1) {
      s0 += __shfl_xor(s0, off, 16); s1 += __shfl_xor(s1, off, 16);
      s2 += __shfl_xor(s2, off, 16); s3 += __shfl_xor(s3, off, 16);
    }
    *(float4*)&al_sm[g][gl][0] =
        make_float4(sc0 / s0, sc1 / s1, sc2 / s2, sc3 / s3);

    int h = gl >> 2;
    int cbase = gl * 8;
    float a0 = 0.f, a1 = 0.f, a2 = 0.f, a3 = 0.f,
          a4 = 0.f, a5 = 0.f, a6 = 0.f, a7 = 0.f;
    for (int j = 0; j < deg; j += 4) {
      #pragma unroll
      for (int u = 0; u < 4; ++u) {
        int idx = j + u;
        bool vU = idx < deg;
        int jj = vU ? idx : 0;
        int   sU  = sr_sm[g][jj];
        float alU = vU ? al_sm[g][jj][h] : 0.f;
        float f[8];
        load8h(&Hm[(size_t)sU * 128 + cbase], f);
        a0 += f[0] * alU; a1 += f[1] * alU; a2 += f[2] * alU; a3 += f[3] * alU;
        a4 += f[4] * alU; a5 += f[5] * alU; a6 += f[6] * alU; a7 += f[7] * alU;
      }
    }
    float4 b0 = *(const float4*)&bias[cbase];
    float4 b1 = *(const float4*)&bias[cbase + 4];
    __half2* dst = (__half2*)&out[(size_t)n * 128 + cbase];
    dst[0] = __floats2half2_rn(fmaxf(a0 + b0.x, 0.f), fmaxf(a1 + b0.y, 0.f));
    dst[1] = __floats2half2_rn(fmaxf(a2 + b0.z, 0.f), fmaxf(a3 + b0.w, 0.f));
    dst[2] = __floats2half2_rn(fmaxf(a4 + b1.x, 0.f), fmaxf(a5 + b1.y, 0.f));
    dst[3] = __floats2half2_rn(fmaxf(a6 + b1.z, 0.f), fmaxf(a7 + b1.w, 0.f));
    return;
  }
  // ---- big role: node per wave ----
  __shared__ float al_sm[4][64][4];
  __shared__ int   sr_sm[4][64];
  int wv = threadIdx.x >> 6, lane = threadIdx.x & 63;
  int widx = (blockIdx.x - SB) * 4 + wv;
  if (widx >= lcnt[16]) return;
  int n = big_list[widx];
  int r0 = rowptr[n], r1 = rowptr[n + 1];
  int deg = r1 - r0;
  int grp = lane >> 4, gl = lane & 15, h = gl >> 2;
  int cbase = gl * 8;
  float4 adn = *(const float4*)&ad[n * 4];

  float a0 = 0.f, a1 = 0.f, a2 = 0.f, a3 = 0.f,
        a4 = 0.f, a5 = 0.f, a6 = 0.f, a7 = 0.f;

  if (deg <= 64) {
    float e0 = -INFINITY, e1 = -INFINITY, e2 = -INFINITY, e3 = -INFINITY;
    int s = 0;
    if (lane < deg) {
      s = srcs[r0 + lane];
      float4 av = *(const float4*)&as[s * 4];
      e0 = leaky(av.x + adn.x); e1 = leaky(av.y + adn.y);
      e2 = leaky(av.z + adn.z); e3 = leaky(av.w + adn.w);
    }
    sr_sm[wv][lane] = s;
    float m0 = e0, m1 = e1, m2 = e2, m3 = e3;
    #pragma unroll
    for (int off = 32; off > 0; off >>= 1) {
      m0 = fmaxf(m0, __shfl_xor(m0, off)); m1 = fmaxf(m1, __shfl_xor(m1, off));
      m2 = fmaxf(m2, __shfl_xor(m2, off)); m3 = fmaxf(m3, __shfl_xor(m3, off));
    }
    float sc0 = (lane < deg) ? __expf(e0 - m0) : 0.f;
    float sc1 = (lane < deg) ? __expf(e1 - m1) : 0.f;
    float sc2 = (lane < deg) ? __expf(e2 - m2) : 0.f;
    float sc3 = (lane < deg) ? __expf(e3 - m3) : 0.f;
    float s0 = sc0, s1 = sc1, s2 = sc2, s3 = sc3;
    #pragma unroll
    for (int off = 32; off > 0; off >>= 1) {
      s0 += __shfl_xor(s0, off); s1 += __shfl_xor(s1, off);
      s2 += __shfl_xor(s2, off); s3 += __shfl_xor(s3, off);
    }
    *(float4*)&al_sm[wv][lane][0] =
        make_float4(sc0 / s0, sc1 / s1, sc2 / s2, sc3 / s3);

    for (int base = 0; base < deg; base += 16) {
      #pragma unroll
      for (int u = 0; u < 4; ++u) {
        int idx = base + grp * 4 + u;
        bool vU = idx < deg;
        int jj = vU ? idx : 0;
        int   sU  = sr_sm[wv][jj];
        float alU = vU ? al_sm[wv][jj][h] : 0.f;
        float f[8];
        load8h(&Hm[(size_t)sU * 128 + cbase], f);
        a0 += f[0] * alU; a1 += f[1] * alU; a2 += f[2] * alU; a3 += f[3] * alU;
        a4 += f[4] * alU; a5 += f[5] * alU; a6 += f[6] * alU; a7 += f[7] * alU;
      }
    }
  } else {
    float m0 = -INFINITY, m1 = -INFINITY, m2 = -INFINITY, m3 = -INFINITY;
    for (int r = r0 + lane; r < r1; r += 64) {
      int s = srcs[r];
      float4 av = *(const float4*)&as[s * 4];
      m0 = fmaxf(m0, leaky(av.x + adn.x)); m1 = fmaxf(m1, leaky(av.y + adn.y));
      m2 = fmaxf(m2, leaky(av.z + adn.z)); m3 = fmaxf(m3, leaky(av.w + adn.w));
    }
    #pragma unroll
    for (int off = 32; off > 0; off >>= 1) {
      m0 = fmaxf(m0, __shfl_xor(m0, off)); m1 = fmaxf(m1, __shfl_xor(m1, off));
      m2 = fmaxf(m2, __shfl_xor(m2, off)); m3 = fmaxf(m3, __shfl_xor(m3, off));
    }
    float s0 = 0.f, s1 = 0.f, s2 = 0.f, s3 = 0.f;
    for (int r = r0 + lane; r < r1; r += 64) {
      int s = srcs[r];
      float4 av = *(const float4*)&as[s * 4];
      s0 += __expf(leaky(av.x + adn.x) - m0); s1 += __expf(leaky(av.y + adn.y) - m1);
      s2 += __expf(leaky(av.z + adn.z) - m2); s3 += __expf(leaky(av.w + adn.w) - m3);
    }
    #pragma unroll
    for (int off = 32; off > 0; off >>= 1) {
      s0 += __shfl_xor(s0, off); s1 += __shfl_xor(s1, off);
      s2 += __shfl_xor(s2, off); s3 += __shfl_xor(s3, off);
    }
    float mhh = (h == 0) ? m0 : (h == 1) ? m1 : (h == 2) ? m2 : m3;
    float inv = 1.f / ((h == 0) ? s0 : (h == 1) ? s1 : (h == 2) ? s2 : s3);
    float adh = (h == 0) ? adn.x : (h == 1) ? adn.y : (h == 2) ? adn.z : adn.w;
    for (int r = r0; r < r1; r += 8) {
      int rA = r + grp, rB = rA + 4;
      bool vA = rA < r1, vB = rB < r1;
      int sA = srcs[vA ? rA : r0];
      int sB = srcs[vB ? rB : r0];
      float avA = as[sA * 4 + h], avB = as[sB * 4 + h];
      float alA = vA ? (__expf(leaky(avA + adh) - mhh) * inv) : 0.f;
      float alB = vB ? (__expf(leaky(avB + adh) - mhh) * inv) : 0.f;
      float fA[8], fB[8];
      load8h(&Hm[(size_t)sA * 128 + cbase], fA);
      load8h(&Hm[(size_t)sB * 128 + cbase], fB);
      a0 += fA[0] * alA + fB[0] * alB; a1 += fA[1] * alA + fB[1] * alB;
      a2 += fA[2] * alA + fB[2] * alB; a3 += fA[3] * alA + fB[3] * alB;
      a4 += fA[4] * alA + fB[4] * alB; a5 += fA[5] * alA + fB[5] * alB;
      a6 += fA[6] * alA + fB[6] * alB; a7 += fA[7] * alA + fB[7] * alB;
    }
  }
  a0 += __shfl_xor(a0, 16); a0 += __shfl_xor(a0, 32);
  a1 += __shfl_xor(a1, 16); a1 += __shfl_xor(a1, 32);
  a2 += __shfl_xor(a2, 16); a2 += __shfl_xor(a2, 32);
  a3 += __shfl_xor(a3, 16); a3 += __shfl_xor(a3, 32);
  a4 += __shfl_xor(a4, 16); a4 += __shfl_xor(a4, 32);
  a5 += __shfl_xor(a5, 16); a5 += __shfl_xor(a5, 32);
  a6 += __shfl_xor(a6, 16); a6 += __shfl_xor(a6, 32);
  a7 += __shfl_xor(a7, 16); a7 += __shfl_xor(a7, 32);
  if (grp == 0) {
    float4 b0 = *(const float4*)&bias[cbase];
    float4 b1 = *(const float4*)&bias[cbase + 4];
    __half2* dst = (__half2*)&out[(size_t)n * 128 + cbase];
    dst[0] = __floats2half2_rn(fmaxf(a0 + b0.x, 0.f), fmaxf(a1 + b0.y, 0.f));
    dst[1] = __floats2half2_rn(fmaxf(a2 + b0.z, 0.f), fmaxf(a3 + b0.w, 0.f));
    dst[2] = __floats2half2_rn(fmaxf(a4 + b1.x, 0.f), fmaxf(a5 + b1.y, 0.f));
    dst[3] = __floats2half2_rn(fmaxf(a6 + b1.z, 0.f), fmaxf(a7 + b1.w, 0.f));
  }
}

// ---------------- layer-2 merged aggregation (out fp32 = d_out) ----------------
__global__ __launch_bounds__(256) void agg2_k(const int* __restrict__ rowptr,
                                              const int* __restrict__ srcs,
                                              const float* __restrict__ as,
                                              const float* __restrict__ ad,
                                              const __half* __restrict__ Hm,
                                              const float* __restrict__ bias,
                                              float* __restrict__ out,
                                              const int* __restrict__ small_list,
                                              const int* __restrict__ big_list,
                                              const int* __restrict__ lcnt, int SB) {
  if (blockIdx.x < (unsigned)SB) {
    __shared__ float al_sm[16][17];
    __shared__ int   sr_sm[16][16];
    int g  = threadIdx.x >> 4;
    int gl = threadIdx.x & 15;
    int gidx = blockIdx.x * 16 + g;
    if (gidx >= lcnt[0]) return;
    int n = small_list[gidx];
    int r0 = rowptr[n];
    int deg = rowptr[n + 1] - r0;
    float adn = ad[n];

    float e = -INFINITY;
    int s = 0;
    if (gl < deg) { s = srcs[r0 + gl]; e = leaky(as[s] + adn); }
    sr_sm[g][gl] = s;
    float m = e;
    #pragma unroll
    for (int off = 8; off > 0; off >>= 1) m = fmaxf(m, __shfl_xor(m, off, 16));
    float sc = (gl < deg) ? __expf(e - m) : 0.f;
    float ssum = sc;
    #pragma unroll
    for (int off = 8; off > 0; off >>= 1) ssum += __shfl_xor(ssum, off, 16);
    al_sm[g][gl] = sc / ssum;

    int cbase = gl * 4;
    float a0 = 0.f, a1 = 0.f, a2 = 0.f, a3 = 0.f;
    for (int j = 0; j < deg; j += 4) {
      #pragma unroll
      for (int u = 0; u < 4; ++u) {
        int idx = j + u;
        bool vU = idx < deg;
        int jj = vU ? idx : 0;
        int   sU  = sr_sm[g][jj];
        float alU = vU ? al_sm[g][jj] : 0.f;
        uint2 hv = *(const uint2*)&Hm[(size_t)sU * 64 + cbase];
        float2 f0 = __half22float2(*(const __half2*)&hv.x);
        float2 f1 = __half22float2(*(const __half2*)&hv.y);
        a0 += f0.x * alU; a1 += f0.y * alU; a2 += f1.x * alU; a3 += f1.y * alU;
      }
    }
    float4 bv = *(const float4*)&bias[cbase];
    f32x4 o;
    o[0] = a0 + bv.x; o[1] = a1 + bv.y; o[2] = a2 + bv.z; o[3] = a3 + bv.w;
    __builtin_nontemporal_store(o, (f32x4*)&out[(size_t)n * 64 + cbase]);
    return;
  }
  __shared__ float al_sm[4][64];
  __shared__ int   sr_sm[4][64];
  int wv = threadIdx.x >> 6, lane = threadIdx.x & 63;
  int widx = (blockIdx.x - SB) * 4 + wv;
  if (widx >= lcnt[16]) return;
  int n = big_list[widx];
  int r0 = rowptr[n], r1 = rowptr[n + 1];
  int deg = r1 - r0;
  int grp = lane >> 4, gl = lane & 15;
  int cbase = gl * 4;
  float adn = ad[n];

  float a0 = 0.f, a1 = 0.f, a2 = 0.f, a3 = 0.f;

  if (deg <= 64) {
    float e = -INFINITY;
    int s = 0;
    if (lane < deg) { s = srcs[r0 + lane]; e = leaky(as[s] + adn); }
    sr_sm[wv][lane] = s;
    float m = e;
    #pragma unroll
    for (int off = 32; off > 0; off >>= 1) m = fmaxf(m, __shfl_xor(m, off));
    float sc = (lane < deg) ? __expf(e - m) : 0.f;
    float ssum = sc;
    #pragma unroll
    for (int off = 32; off > 0; off >>= 1) ssum += __shfl_xor(ssum, off);
    al_sm[wv][lane] = sc / ssum;

    for (int base = 0; base < deg; base += 16) {
      #pragma unroll
      for (int u = 0; u < 4; ++u) {
        int idx = base + grp * 4 + u;
        bool vU = idx < deg;
        int jj = vU ? idx : 0;
        int   sU  = sr_sm[wv][jj];
        float alU = vU ? al_sm[wv][jj] : 0.f;
        uint2 hv = *(const uint2*)&Hm[(size_t)sU * 64 + cbase];
        float2 f0 = __half22float2(*(const __half2*)&hv.x);
        float2 f1 = __half22float2(*(const __half2*)&hv.y);
        a0 += f0.x * alU; a1 += f0.y * alU; a2 += f1.x * alU; a3 += f1.y * alU;
      }
    }
  } else {
    float mh = -INFINITY;
    for (int r = r0 + lane; r < r1; r += 64)
      mh = fmaxf(mh, leaky(as[srcs[r]] + adn));
    #pragma unroll
    for (int off = 32; off > 0; off >>= 1) mh = fmaxf(mh, __shfl_xor(mh, off));
    float ssum = 0.f;
    for (int r = r0 + lane; r < r1; r += 64)
      ssum += __expf(leaky(as[srcs[r]] + adn) - mh);
    #pragma unroll
    for (int off = 32; off > 0; off >>= 1) ssum += __shfl_xor(ssum, off);
    float inv = 1.f / ssum;
    for (int r = r0; r < r1; r += 8) {
      int rA = r + grp, rB = rA + 4;
      bool vA = rA < r1, vB = rB < r1;
      int sA = srcs[vA ? rA : r0];
      int sB = srcs[vB ? rB : r0];
      float alA = vA ? (__expf(leaky(as[sA] + adn) - mh) * inv) : 0.f;
      float alB = vB ? (__expf(leaky(as[sB] + adn) - mh) * inv) : 0.f;
      uint2 hvA = *(const uint2*)&Hm[(size_t)sA * 64 + cbase];
      uint2 hvB = *(const uint2*)&Hm[(size_t)sB * 64 + cbase];
      float2 fA0 = __half22float2(*(const __half2*)&hvA.x);
      float2 fA1 = __half22float2(*(const __half2*)&hvA.y);
      float2 fB0 = __half22float2(*(const __half2*)&hvB.x);
      float2 fB1 = __half22float2(*(const __half2*)&hvB.y);
      a0 += fA0.x * alA + fB0.x * alB; a1 += fA0.y * alA + fB0.y * alB;
      a2 += fA1.x * alA + fB1.x * alB; a3 += fA1.y * alA + fB1.y * alB;
    }
  }
  a0 += __shfl_xor(a0, 16); a0 += __shfl_xor(a0, 32);
  a1 += __shfl_xor(a1, 16); a1 += __shfl_xor(a1, 32);
  a2 += __shfl_xor(a2, 16); a2 += __shfl_xor(a2, 32);
  a3 += __shfl_xor(a3, 16); a3 += __shfl_xor(a3, 32);
  if (grp == 0) {
    float4 bv = *(const float4*)&bias[cbase];
    f32x4 o;
    o[0] = a0 + bv.x; o[1] = a1 + bv.y; o[2] = a2 + bv.z; o[3] = a3 + bv.w;
    __builtin_nontemporal_store(o, (f32x4*)&out[(size_t)n * 64 + cbase]);
  }
}

extern "C" void kernel_launch(void* const* d_in, const int* in_sizes, int n_in,
                              void* d_out, int out_size, void* d_ws, size_t ws_size,
                              hipStream_t stream) {
  const float* x   = (const float*)d_in[0];
  const int*   ei  = (const int*)d_in[1];
  // d_in[2] edge_weight: unused by GATConv (edge_dim unset)
  const float* W1  = (const float*)d_in[3];
  const float* aS1 = (const float*)d_in[4];
  const float* aD1 = (const float*)d_in[5];
  const float* b1  = (const float*)d_in[6];
  const float* W2  = (const float*)d_in[7];
  const float* aS2 = (const float*)d_in[8];
  const float* aD2 = (const float*)d_in[9];
  const float* b2  = (const float*)d_in[10];

  const int N  = in_sizes[0] / 128;
  const int E  = in_sizes[2];
  const int ET = E + N;
  const int NB = (N + 127) >> 7;

  float* ws    = (float*)d_ws;
  __half* h1h  = (__half*)ws;                  // N*128 halfs
  __half* o1h  = (__half*)(ws + (size_t)N * 64);  // N*128 halfs (out1, fp16)
  float* as1   = ws + (size_t)N * 128;         // 4N
  float* ad1   = as1  + (size_t)4 * N;         // 4N
  float* as2   = ad1  + (size_t)4 * N;         // N
  float* ad2   = as2  + (size_t)N;             // N
  int*   lcnt    = (int*)(ad2 + (size_t)N);    // 32
  int*   rowptr  = lcnt + 32;                  // N+1
  int*   bbase   = rowptr + N + 1;             // NB+1
  int*   blkpref = bbase + NB + 1;             // NB*NBLKA
  int*   small_list = blkpref + NB * NBLKA;    // N
  int*   big_list   = small_list + N;          // N
  int*   srcs   = big_list + N;                // ET
  _Float16* w1t = (_Float16*)(srcs + ET);      // 128*128 halfs
  _Float16* w2t = w1t + 128 * 128;             // 64*128 halfs
  int*   pairs  = (int*)ws;                    // ET ints, aliased onto h1h
  __half* h2h  = h1h;                          // alias (h1h dead after agg1)
  float* out  = (float*)d_out;                 // N*64

  const int gb = (N + 63) / 64;
  const int sb = (N + 15) / 16;
  const int bb = (N + 3) / 4;

  // ---- CSR build (+ W transpose in histc block 0) ----
  histc_k<<<NBLKA, 256, 0, stream>>>(ei, E, ET, blkpref, NB, W1, W2, w1t, w2t, lcnt);
  scan_blk_k<<<NB, 256, 0, stream>>>(blkpref, bbase, lcnt, rowptr, NB, N, ET);
  passA_k<<<NBLKA, 256, 0, stream>>>(ei, E, ET, bbase, blkpref, pairs, NB);
  passB_k<<<NB, 256, 0, stream>>>(pairs, bbase, rowptr, srcs,
                                  small_list, big_list, lcnt, N);

  // ---- layer 1 ----
  gemm1_k<<<gb, 256, 0, stream>>>(x, w1t, aS1, aD1, h1h, as1, ad1, N);
  agg1_k<<<sb + bb, 256, 0, stream>>>(rowptr, srcs, as1, ad1, h1h, b1, o1h,
                                      small_list, big_list, lcnt, sb);

  // ---- layer 2 ----
  gemm2_k<<<gb, 256, 0, stream>>>(o1h, w2t, aS2, aD2, h2h, as2, ad2, N);
  agg2_k<<<sb + bb, 256, 0, stream>>>(rowptr, srcs, as2, ad2, h2h, b2, out,
                                      small_list, big_list, lcnt, sb);
}

// Round 6
// 215.535 us; speedup vs baseline: 1.1971x; 1.1429x over previous
//
#include <hip/hip_runtime.h>
#include <hip/hip_fp16.h>
#include <math.h>

// GAT (2 layers) on MI355X — radix CSR + merged degree-bucketed aggregation.
// R1: gemm1/gemm2 MFMA (16x16x32 f16, fp32 accum).  [216.4 us]
// R5: exact R1 base (all R2-R4 NT/fused-scan artifacts removed) + gemm1
//     co-launched with histc as one kernel (independent work, block-role
//     split; gemm1 blocks transpose W1 in-block to avoid cross-block race).

#define NEG_SLOPE 0.2f
#define NBLKA 256
#define MAXNB 512
#define LDH 136   // padded halfs per LDS row

typedef _Float16 f16x8 __attribute__((ext_vector_type(8)));
typedef float f32x4 __attribute__((ext_vector_type(4)));
typedef unsigned int u32x4 __attribute__((ext_vector_type(4)));

__device__ __forceinline__ float leaky(float v) { return v > 0.f ? v : NEG_SLOPE * v; }

// ---------------- fused: CSR histogram (blocks < NBLKA) + GEMM1 (rest) ----------------
__global__ __launch_bounds__(256) void histc_gemm1_k(const int* __restrict__ ei, int E, int ET,
                                                     int* __restrict__ blkpref, int NB,
                                                     const float* __restrict__ W1,
                                                     const float* __restrict__ W2,
                                                     _Float16* __restrict__ w2t,
                                                     const float* __restrict__ X,
                                                     const float* __restrict__ aw_s,
                                                     const float* __restrict__ aw_d,
                                                     __half* __restrict__ Hh,
                                                     float* __restrict__ as,
                                                     float* __restrict__ ad, int N) {
  __shared__ float smemf[13056];   // 52224 B: gemm path xs+wt; hist path lhist
  int t = threadIdx.x;
  if (blockIdx.x < NBLKA) {
    // ---- histogram role ----
    int* lhist = (int*)smemf;
    int chunk = (ET + NBLKA - 1) / NBLKA;
    int e0 = blockIdx.x * chunk, e1 = min(ET, e0 + chunk);
    for (int b = t; b < NB; b += 256) lhist[b] = 0;
    __syncthreads();
    for (int e = e0 + t; e < e1; e += 256) {
      int d = (e < E) ? ei[E + e] : (e - E);
      atomicAdd(&lhist[d >> 7], 1);
    }
    __syncthreads();
    for (int b = t; b < NB; b += 256)
      blkpref[b * NBLKA + blockIdx.x] = lhist[b];
    // W2T [64n][128k] fp16 — block 0 only (consumed by gemm2, later launch)
    if (blockIdx.x == 0 && t < 64) {
      union { _Float16 h[8]; u32x4 u; } buf;
      for (int k0 = 0; k0 < 128; k0 += 8) {
        #pragma unroll
        for (int u = 0; u < 8; ++u) buf.h[u] = (_Float16)W2[(k0 + u) * 64 + t];
        *(u32x4*)&w2t[t * 128 + k0] = buf.u;
      }
    }
    return;
  }
  // ---- GEMM1 role: h1h = X(fp32->fp16) @ W1, + alpha1 ----
  _Float16* xs = (_Float16*)smemf;            // [64 * LDH]
  _Float16* wt = xs + 64 * LDH;               // [128 * LDH]
  int n0 = (blockIdx.x - NBLKA) * 64;
  // stage W1 transposed: W1 is [128k][128n] fp32; wt[n][k] fp16
  for (int i = t; i < 4096; i += 256) {
    int k = i >> 5, n4 = (i & 31) * 4;
    float4 wv = *(const float4*)&W1[k * 128 + n4];
    wt[(n4 + 0) * LDH + k] = (_Float16)wv.x;
    wt[(n4 + 1) * LDH + k] = (_Float16)wv.y;
    wt[(n4 + 2) * LDH + k] = (_Float16)wv.z;
    wt[(n4 + 3) * LDH + k] = (_Float16)wv.w;
  }
  // stage X fp32 -> fp16: 64 rows x 32 float4
  for (int i = t; i < 2048; i += 256) {
    int r = i >> 5, c4 = i & 31;
    int n = n0 + r;
    float4 xv = (n < N) ? *(const float4*)&X[(size_t)n * 128 + c4 * 4]
                        : make_float4(0.f, 0.f, 0.f, 0.f);
    __half2 h0 = __floats2half2_rn(xv.x, xv.y);
    __half2 h1 = __floats2half2_rn(xv.z, xv.w);
    uint2 u; u.x = *(unsigned*)&h0; u.y = *(unsigned*)&h1;
    *(uint2*)&xs[r * LDH + c4 * 4] = u;
  }
  __syncthreads();
  int wv = t >> 6, l = t & 63;
  int row16 = l & 15, kg = l >> 4;
  f32x4 acc[8];
  #pragma unroll
  for (int j = 0; j < 8; ++j) acc[j] = (f32x4){0.f, 0.f, 0.f, 0.f};
  #pragma unroll
  for (int kk = 0; kk < 4; ++kk) {
    int kbase = kk * 32 + kg * 8;
    f16x8 afr = *(f16x8*)&xs[(wv * 16 + row16) * LDH + kbase];
    #pragma unroll
    for (int j = 0; j < 8; ++j) {
      f16x8 bfr = *(f16x8*)&wt[(j * 16 + row16) * LDH + kbase];
      acc[j] = __builtin_amdgcn_mfma_f32_16x16x32_f16(afr, bfr, acc[j], 0, 0, 0);
    }
  }
  __syncthreads();
  #pragma unroll
  for (int j = 0; j < 8; ++j) {
    int col = j * 16 + row16;
    #pragma unroll
    for (int r = 0; r < 4; ++r) {
      int row = wv * 16 + kg * 4 + r;
      xs[row * LDH + col] = (_Float16)acc[j][r];
    }
  }
  __syncthreads();
  for (int i = t; i < 1024; i += 256) {
    int r = i >> 4, c8 = i & 15;
    int n = n0 + r;
    if (n < N) ((u32x4*)Hh)[(size_t)n * 16 + c8] = *(u32x4*)&xs[r * LDH + c8 * 8];
  }
  {
    int r = t >> 2, h = t & 3;
    int n = n0 + r;
    float ps = 0.f, pd = 0.f;
    #pragma unroll
    for (int q = 0; q < 4; ++q) {
      f16x8 hv = *(f16x8*)&xs[r * LDH + h * 32 + q * 8];
      float4 s0 = *(const float4*)&aw_s[h * 32 + q * 8];
      float4 s1 = *(const float4*)&aw_s[h * 32 + q * 8 + 4];
      float4 d0 = *(const float4*)&aw_d[h * 32 + q * 8];
      float4 d1 = *(const float4*)&aw_d[h * 32 + q * 8 + 4];
      ps += (float)hv[0] * s0.x + (float)hv[1] * s0.y + (float)hv[2] * s0.z + (float)hv[3] * s0.w
          + (float)hv[4] * s1.x + (float)hv[5] * s1.y + (float)hv[6] * s1.z + (float)hv[7] * s1.w;
      pd += (float)hv[0] * d0.x + (float)hv[1] * d0.y + (float)hv[2] * d0.z + (float)hv[3] * d0.w
          + (float)hv[4] * d1.x + (float)hv[5] * d1.y + (float)hv[6] * d1.z + (float)hv[7] * d1.w;
    }
    if (n < N) { as[n * 4 + h] = ps; ad[n * 4 + h] = pd; }
  }
}

__global__ __launch_bounds__(256) void scan_blk_k(int* __restrict__ blkpref,
                                                  int* __restrict__ bbase) {
  __shared__ int sm[NBLKA];
  int b = blockIdx.x, t = threadIdx.x;
  int v = blkpref[b * NBLKA + t];
  sm[t] = v;
  __syncthreads();
  #pragma unroll
  for (int off = 1; off < NBLKA; off <<= 1) {
    int x = (t >= off) ? sm[t - off] : 0;
    __syncthreads();
    sm[t] += x;
    __syncthreads();
  }
  blkpref[b * NBLKA + t] = sm[t] - v;
  if (t == NBLKA - 1) bbase[b] = sm[t];
}

__global__ __launch_bounds__(512) void scan_bkt_k(int* __restrict__ bbase,
                                                  int* __restrict__ lcnt,
                                                  int* __restrict__ rowptr,
                                                  int NB, int N, int ET) {
  __shared__ int sm[512];
  int t = threadIdx.x;
  int v = (t < NB) ? bbase[t] : 0;
  sm[t] = v;
  __syncthreads();
  #pragma unroll
  for (int off = 1; off < 512; off <<= 1) {
    int x = (t >= off) ? sm[t - off] : 0;
    __syncthreads();
    sm[t] += x;
    __syncthreads();
  }
  int excl = sm[t] - v;
  if (t <= NB) bbase[t] = excl;
  if (t == 0) { lcnt[0] = 0; lcnt[16] = 0; rowptr[N] = ET; }
}

__global__ __launch_bounds__(256) void passA_k(const int* __restrict__ ei, int E, int ET,
                                               const int* __restrict__ bbase,
                                               const int* __restrict__ blkpref,
                                               int* __restrict__ pairs, int NB) {
  __shared__ int lcur[MAXNB];
  int chunk = (ET + NBLKA - 1) / NBLKA;
  int e0 = blockIdx.x * chunk, e1 = min(ET, e0 + chunk);
  for (int b = threadIdx.x; b < NB; b += 256)
    lcur[b] = bbase[b] + blkpref[b * NBLKA + blockIdx.x];
  __syncthreads();
  for (int e = e0 + threadIdx.x; e < e1; e += 256) {
    int s, d;
    if (e < E) { s = ei[e]; d = ei[E + e]; } else { s = d = e - E; }
    int b = d >> 7;
    int pos = atomicAdd(&lcur[b], 1);
    pairs[pos] = ((d & 127) << 17) | s;
  }
}

__global__ __launch_bounds__(256) void passB_k(const int* __restrict__ pairs,
                                               const int* __restrict__ bbase,
                                               int* __restrict__ rowptr,
                                               int* __restrict__ srcs,
                                               int* __restrict__ small_list,
                                               int* __restrict__ big_list,
                                               int* __restrict__ lcnt, int N) {
  __shared__ int ncnt[128], spre[128], lcur[128];
  __shared__ int wcS[2], wcB[2], bS, bB;
  int b = blockIdx.x, t = threadIdx.x;
  int nb0 = b << 7;
  int nn = min(128, N - nb0);
  int e0 = bbase[b], e1 = bbase[b + 1];
  if (t < 128) ncnt[t] = 0;
  __syncthreads();
  for (int r = e0 + t; r < e1; r += 256)
    atomicAdd(&ncnt[pairs[r] >> 17], 1);
  __syncthreads();
  if (t < 128) spre[t] = ncnt[t];
  __syncthreads();
  #pragma unroll
  for (int off = 1; off < 128; off <<= 1) {
    int x = (t < 128 && t >= off) ? spre[t - off] : 0;
    __syncthreads();
    if (t < 128) spre[t] += x;
    __syncthreads();
  }
  if (t < nn) {
    int base = e0 + spre[t] - ncnt[t];
    rowptr[nb0 + t] = base;
    lcur[t] = base;
  }
  __syncthreads();
  for (int r = e0 + t; r < e1; r += 256) {
    int p = pairs[r];
    int pos = atomicAdd(&lcur[p >> 17], 1);
    srcs[pos] = p & 0x1FFFF;
  }
  int lane = t & 63, wv = t >> 6;
  bool valid = (t < nn);
  int deg = valid ? ncnt[t] : 0;
  bool isS = valid && (deg <= 16);
  bool isB = valid && (deg > 16);
  unsigned long long ms = __ballot(isS);
  unsigned long long mb = __ballot(isB);
  if (lane == 0 && wv < 2) { wcS[wv] = __popcll(ms); wcB[wv] = __popcll(mb); }
  __syncthreads();
  if (t == 0) {
    bS = atomicAdd(&lcnt[0],  wcS[0] + wcS[1]);
    bB = atomicAdd(&lcnt[16], wcB[0] + wcB[1]);
  }
  __syncthreads();
  unsigned long long below = (lane == 0) ? 0ull : (~0ull >> (64 - lane));
  int offS = bS + ((wv == 1) ? wcS[0] : 0);
  int offB = bB + ((wv == 1) ? wcB[0] : 0);
  if (isS) small_list[offS + __popcll(ms & below)] = nb0 + t;
  if (isB) big_list[offB + __popcll(mb & below)]   = nb0 + t;
}

// ---------------- GEMM2 (MFMA) + alpha2: h2h = o1h(fp16) @ W2 ----------------
__global__ __launch_bounds__(256) void gemm2_k(const __half* __restrict__ X,
                                               const _Float16* __restrict__ WT,
                                               const float* __restrict__ aw_s,
                                               const float* __restrict__ aw_d,
                                               __half* __restrict__ Hh,
                                               float* __restrict__ as,
                                               float* __restrict__ ad, int N) {
  __shared__ _Float16 xs[64 * LDH];
  __shared__ _Float16 wt[64 * LDH];
  int t = threadIdx.x;
  int n0 = blockIdx.x * 64;
  for (int i = t; i < 1024; i += 256) {
    int r = i >> 4, c8 = i & 15;
    *(u32x4*)&wt[r * LDH + c8 * 8] = ((const u32x4*)WT)[i];
  }
  for (int i = t; i < 1024; i += 256) {
    int r = i >> 4, c8 = i & 15;
    int n = n0 + r;
    u32x4 v = (n < N) ? ((const u32x4*)X)[(size_t)n * 16 + c8] : (u32x4){0, 0, 0, 0};
    *(u32x4*)&xs[r * LDH + c8 * 8] = v;
  }
  __syncthreads();
  int wv = t >> 6, l = t & 63;
  int row16 = l & 15, kg = l >> 4;
  f32x4 acc[4];
  #pragma unroll
  for (int j = 0; j < 4; ++j) acc[j] = (f32x4){0.f, 0.f, 0.f, 0.f};
  #pragma unroll
  for (int kk = 0; kk < 4; ++kk) {
    int kbase = kk * 32 + kg * 8;
    f16x8 afr = *(f16x8*)&xs[(wv * 16 + row16) * LDH + kbase];
    #pragma unroll
    for (int j = 0; j < 4; ++j) {
      f16x8 bfr = *(f16x8*)&wt[(j * 16 + row16) * LDH + kbase];
      acc[j] = __builtin_amdgcn_mfma_f32_16x16x32_f16(afr, bfr, acc[j], 0, 0, 0);
    }
  }
  __syncthreads();
  #pragma unroll
  for (int j = 0; j < 4; ++j) {
    int col = j * 16 + row16;
    #pragma unroll
    for (int r = 0; r < 4; ++r) {
      int row = wv * 16 + kg * 4 + r;
      xs[row * LDH + col] = (_Float16)acc[j][r];
    }
  }
  __syncthreads();
  for (int i = t; i < 512; i += 256) {
    int r = i >> 3, c8 = i & 7;
    int n = n0 + r;
    if (n < N) ((u32x4*)Hh)[(size_t)n * 8 + c8] = *(u32x4*)&xs[r * LDH + c8 * 8];
  }
  {
    int r = t >> 2, q = t & 3;
    int n = n0 + r;
    float ps = 0.f, pd = 0.f;
    #pragma unroll
    for (int qq = 0; qq < 2; ++qq) {
      f16x8 hv = *(f16x8*)&xs[r * LDH + q * 16 + qq * 8];
      float4 s0 = *(const float4*)&aw_s[q * 16 + qq * 8];
      float4 s1 = *(const float4*)&aw_s[q * 16 + qq * 8 + 4];
      float4 d0 = *(const float4*)&aw_d[q * 16 + qq * 8];
      float4 d1 = *(const float4*)&aw_d[q * 16 + qq * 8 + 4];
      ps += (float)hv[0] * s0.x + (float)hv[1] * s0.y + (float)hv[2] * s0.z + (float)hv[3] * s0.w
          + (float)hv[4] * s1.x + (float)hv[5] * s1.y + (float)hv[6] * s1.z + (float)hv[7] * s1.w;
      pd += (float)hv[0] * d0.x + (float)hv[1] * d0.y + (float)hv[2] * d0.z + (float)hv[3] * d0.w
          + (float)hv[4] * d1.x + (float)hv[5] * d1.y + (float)hv[6] * d1.z + (float)hv[7] * d1.w;
    }
    ps += __shfl_xor(ps, 1); ps += __shfl_xor(ps, 2);
    pd += __shfl_xor(pd, 1); pd += __shfl_xor(pd, 2);
    if (q == 0 && n < N) { as[n] = ps; ad[n] = pd; }
  }
}

__device__ __forceinline__ void load8h(const __half* p, float* f) {
  uint4 hv = *(const uint4*)p;
  float2 f0 = __half22float2(*(const __half2*)&hv.x);
  float2 f1 = __half22float2(*(const __half2*)&hv.y);
  float2 f2 = __half22float2(*(const __half2*)&hv.z);
  float2 f3 = __half22float2(*(const __half2*)&hv.w);
  f[0] = f0.x; f[1] = f0.y; f[2] = f1.x; f[3] = f1.y;
  f[4] = f2.x; f[5] = f2.y; f[6] = f3.x; f[7] = f3.y;
}

// ---------------- layer-1 merged aggregation (out fp16) ----------------
__global__ __launch_bounds__(256) void agg1_k(const int* __restrict__ rowptr,
                                              const int* __restrict__ srcs,
                                              const float* __restrict__ as,
                                              const float* __restrict__ ad,
                                              const __half* __restrict__ Hm,
                                              const float* __restrict__ bias,
                                              __half* __restrict__ out,
                                              const int* __restrict__ small_list,
                                              const int* __restrict__ big_list,
                                              const int* __restrict__ lcnt, int SB) {
  if (blockIdx.x < (unsigned)SB) {
    // ---- small role: node per 16-lane group ----
    __shared__ float al_sm[16][17][4];
    __shared__ int   sr_sm[16][16];
    int g  = threadIdx.x >> 4;
    int gl = threadIdx.x & 15;
    int gidx = blockIdx.x * 16 + g;
    if (gidx >= lcnt[0]) return;
    int n = small_list[gidx];
    int r0 = rowptr[n];
    int deg = rowptr[n + 1] - r0;
    float4 adn = *(const float4*)&ad[n * 4];

    float e0 = -INFINITY, e1 = -INFINITY, e2 = -INFINITY, e3 = -INFINITY;
    int s = 0;
    if (gl < deg) {
      s = srcs[r0 + gl];
      float4 av = *(const float4*)&as[s * 4];
      e0 = leaky(av.x + adn.x); e1 = leaky(av.y + adn.y);
      e2 = leaky(av.z + adn.z); e3 = leaky(av.w + adn.w);
    }
    sr_sm[g][gl] = s;
    float m0 = e0, m1 = e1, m2 = e2, m3 = e3;
    #pragma unroll
    for (int off = 8; off > 0; off >>= 1) {
      m0 = fmaxf(m0, __shfl_xor(m0, off, 16)); m1 = fmaxf(m1, __shfl_xor(m1, off, 16));
      m2 = fmaxf(m2, __shfl_xor(m2, off, 16)); m3 = fmaxf(m3, __shfl_xor(m3, off, 16));
    }
    float sc0 = (gl < deg) ? __expf(e0 - m0) : 0.f;
    float sc1 = (gl < deg) ? __expf(e1 - m1) : 0.f;
    float sc2 = (gl < deg) ? __expf(e2 - m2) : 0.f;
    float sc3 = (gl < deg) ? __expf(e3 - m3) : 0.f;
    float s0 = sc0, s1 = sc1, s2 = sc2, s3 = sc3;
    #pragma unroll
    for (int off = 8; off > 0; off >>= 1) {
      s0 += __shfl_xor(s0, off, 16); s1 += __shfl_xor(s1, off, 16);
      s2 += __shfl_xor(s2, off, 16); s3 += __shfl_xor(s3, off, 16);
    }
    *(float4*)&al_sm[g][gl][0] =
        make_float4(sc0 / s0, sc1 / s1, sc2 / s2, sc3 / s3);

    int h = gl >> 2;
    int cbase = gl * 8;
    float a0 = 0.f, a1 = 0.f, a2 = 0.f, a3 = 0.f,
          a4 = 0.f, a5 = 0.f, a6 = 0.f, a7 = 0.f;
    for (int j = 0; j < deg; j += 4) {
      #pragma unroll
      for (int u = 0; u < 4; ++u) {
        int idx = j + u;
        bool vU = idx < deg;
        int jj = vU ? idx : 0;
        int   sU  = sr_sm[g][jj];
        float alU = vU ? al_sm[g][jj][h] : 0.f;
        float f[8];
        load8h(&Hm[(size_t)sU * 128 + cbase], f);
        a0 += f[0] * alU; a1 += f[1] * alU; a2 += f[2] * alU; a3 += f[3] * alU;
        a4 += f[4] * alU; a5 += f[5] * alU; a6 += f[6] * alU; a7 += f[7] * alU;
      }
    }
    float4 b0 = *(const float4*)&bias[cbase];
    float4 b1 = *(const float4*)&bias[cbase + 4];
    __half2* dst = (__half2*)&out[(size_t)n * 128 + cbase];
    dst[0] = __floats2half2_rn(fmaxf(a0 + b0.x, 0.f), fmaxf(a1 + b0.y, 0.f));
    dst[1] = __floats2half2_rn(fmaxf(a2 + b0.z, 0.f), fmaxf(a3 + b0.w, 0.f));
    dst[2] = __floats2half2_rn(fmaxf(a4 + b1.x, 0.f), fmaxf(a5 + b1.y, 0.f));
    dst[3] = __floats2half2_rn(fmaxf(a6 + b1.z, 0.f), fmaxf(a7 + b1.w, 0.f));
    return;
  }
  // ---- big role: node per wave ----
  __shared__ float al_sm[4][64][4];
  __shared__ int   sr_sm[4][64];
  int wv = threadIdx.x >> 6, lane = threadIdx.x & 63;
  int widx = (blockIdx.x - SB) * 4 + wv;
  if (widx >= lcnt[16]) return;
  int n = big_list[widx];
  int r0 = rowptr[n], r1 = rowptr[n + 1];
  int deg = r1 - r0;
  int grp = lane >> 4, gl = lane & 15, h = gl >> 2;
  int cbase = gl * 8;
  float4 adn = *(const float4*)&ad[n * 4];

  float a0 = 0.f, a1 = 0.f, a2 = 0.f, a3 = 0.f,
        a4 = 0.f, a5 = 0.f, a6 = 0.f, a7 = 0.f;

  if (deg <= 64) {
    float e0 = -INFINITY, e1 = -INFINITY, e2 = -INFINITY, e3 = -INFINITY;
    int s = 0;
    if (lane < deg) {
      s = srcs[r0 + lane];
      float4 av = *(const float4*)&as[s * 4];
      e0 = leaky(av.x + adn.x); e1 = leaky(av.y + adn.y);
      e2 = leaky(av.z + adn.z); e3 = leaky(av.w + adn.w);
    }
    sr_sm[wv][lane] = s;
    float m0 = e0, m1 = e1, m2 = e2, m3 = e3;
    #pragma unroll
    for (int off = 32; off > 0; off >>= 1) {
      m0 = fmaxf(m0, __shfl_xor(m0, off)); m1 = fmaxf(m1, __shfl_xor(m1, off));
      m2 = fmaxf(m2, __shfl_xor(m2, off)); m3 = fmaxf(m3, __shfl_xor(m3, off));
    }
    float sc0 = (lane < deg) ? __expf(e0 - m0) : 0.f;
    float sc1 = (lane < deg) ? __expf(e1 - m1) : 0.f;
    float sc2 = (lane < deg) ? __expf(e2 - m2) : 0.f;
    float sc3 = (lane < deg) ? __expf(e3 - m3) : 0.f;
    float s0 = sc0, s1 = sc1, s2 = sc2, s3 = sc3;
    #pragma unroll
    for (int off = 32; off > 0; off >>= 1) {
      s0 += __shfl_xor(s0, off); s1 += __shfl_xor(s1, off);
      s2 += __shfl_xor(s2, off); s3 += __shfl_xor(s3, off);
    }
    *(float4*)&al_sm[wv][lane][0] =
        make_float4(sc0 / s0, sc1 / s1, sc2 / s2, sc3 / s3);

    for (int base = 0; base < deg; base += 16) {
      #pragma unroll
      for (int u = 0; u < 4; ++u) {
        int idx = base + grp * 4 + u;
        bool vU = idx < deg;
        int jj = vU ? idx : 0;
        int   sU  = sr_sm[wv][jj];
        float alU = vU ? al_sm[wv][jj][h] : 0.f;
        float f[8];
        load8h(&Hm[(size_t)sU * 128 + cbase], f);
        a0 += f[0] * alU; a1 += f[1] * alU; a2 += f[2] * alU; a3 += f[3] * alU;
        a4 += f[4] * alU; a5 += f[5] * alU; a6 += f[6] * alU; a7 += f[7] * alU;
      }
    }
  } else {
    float m0 = -INFINITY, m1 = -INFINITY, m2 = -INFINITY, m3 = -INFINITY;
    for (int r = r0 + lane; r < r1; r += 64) {
      int s = srcs[r];
      float4 av = *(const float4*)&as[s * 4];
      m0 = fmaxf(m0, leaky(av.x + adn.x)); m1 = fmaxf(m1, leaky(av.y + adn.y));
      m2 = fmaxf(m2, leaky(av.z + adn.z)); m3 = fmaxf(m3, leaky(av.w + adn.w));
    }
    #pragma unroll
    for (int off = 32; off > 0; off >>= 1) {
      m0 = fmaxf(m0, __shfl_xor(m0, off)); m1 = fmaxf(m1, __shfl_xor(m1, off));
      m2 = fmaxf(m2, __shfl_xor(m2, off)); m3 = fmaxf(m3, __shfl_xor(m3, off));
    }
    float s0 = 0.f, s1 = 0.f, s2 = 0.f, s3 = 0.f;
    for (int r = r0 + lane; r < r1; r += 64) {
      int s = srcs[r];
      float4 av = *(const float4*)&as[s * 4];
      s0 += __expf(leaky(av.x + adn.x) - m0); s1 += __expf(leaky(av.y + adn.y) - m1);
      s2 += __expf(leaky(av.z + adn.z) - m2); s3 += __expf(leaky(av.w + adn.w) - m3);
    }
    #pragma unroll
    for (int off = 32; off > 0; off >>= 1) {
      s0 += __shfl_xor(s0, off); s1 += __shfl_xor(s1, off);
      s2 += __shfl_xor(s2, off); s3 += __shfl_xor(s3, off);
    }
    float mhh = (h == 0) ? m0 : (h == 1) ? m1 : (h == 2) ? m2 : m3;
    float inv = 1.f / ((h == 0) ? s0 : (h == 1) ? s1 : (h == 2) ? s2 : s3);
    float adh = (h == 0) ? adn.x : (h == 1) ? adn.y : (h == 2) ? adn.z : adn.w;
    for (int r = r0; r < r1; r += 8) {
      int rA = r + grp, rB = rA + 4;
      bool vA = rA < r1, vB = rB < r1;
      int sA = srcs[vA ? rA : r0];
      int sB = srcs[vB ? rB : r0];
      float avA = as[sA * 4 + h], avB = as[sB * 4 + h];
      float alA = vA ? (__expf(leaky(avA + adh) - mhh) * inv) : 0.f;
      float alB = vB ? (__expf(leaky(avB + adh) - mhh) * inv) : 0.f;
      float fA[8], fB[8];
      load8h(&Hm[(size_t)sA * 128 + cbase], fA);
      load8h(&Hm[(size_t)sB * 128 + cbase], fB);
      a0 += fA[0] * alA + fB[0] * alB; a1 += fA[1] * alA + fB[1] * alB;
      a2 += fA[2] * alA + fB[2] * alB; a3 += fA[3] * alA + fB[3] * alB;
      a4 += fA[4] * alA + fB[4] * alB; a5 += fA[5] * alA + fB[5] * alB;
      a6 += fA[6] * alA + fB[6] * alB; a7 += fA[7] * alA + fB[7] * alB;
    }
  }
  a0 += __shfl_xor(a0, 16); a0 += __shfl_xor(a0, 32);
  a1 += __shfl_xor(a1, 16); a1 += __shfl_xor(a1, 32);
  a2 += __shfl_xor(a2, 16); a2 += __shfl_xor(a2, 32);
  a3 += __shfl_xor(a3, 16); a3 += __shfl_xor(a3, 32);
  a4 += __shfl_xor(a4, 16); a4 += __shfl_xor(a4, 32);
  a5 += __shfl_xor(a5, 16); a5 += __shfl_xor(a5, 32);
  a6 += __shfl_xor(a6, 16); a6 += __shfl_xor(a6, 32);
  a7 += __shfl_xor(a7, 16); a7 += __shfl_xor(a7, 32);
  if (grp == 0) {
    float4 b0 = *(const float4*)&bias[cbase];
    float4 b1 = *(const float4*)&bias[cbase + 4];
    __half2* dst = (__half2*)&out[(size_t)n * 128 + cbase];
    dst[0] = __floats2half2_rn(fmaxf(a0 + b0.x, 0.f), fmaxf(a1 + b0.y, 0.f));
    dst[1] = __floats2half2_rn(fmaxf(a2 + b0.z, 0.f), fmaxf(a3 + b0.w, 0.f));
    dst[2] = __floats2half2_rn(fmaxf(a4 + b1.x, 0.f), fmaxf(a5 + b1.y, 0.f));
    dst[3] = __floats2half2_rn(fmaxf(a6 + b1.z, 0.f), fmaxf(a7 + b1.w, 0.f));
  }
}

// ---------------- layer-2 merged aggregation (out fp32 = d_out) ----------------
__global__ __launch_bounds__(256) void agg2_k(const int* __restrict__ rowptr,
                                              const int* __restrict__ srcs,
                                              const float* __restrict__ as,
                                              const float* __restrict__ ad,
                                              const __half* __restrict__ Hm,
                                              const float* __restrict__ bias,
                                              float* __restrict__ out,
                                              const int* __restrict__ small_list,
                                              const int* __restrict__ big_list,
                                              const int* __restrict__ lcnt, int SB) {
  if (blockIdx.x < (unsigned)SB) {
    __shared__ float al_sm[16][17];
    __shared__ int   sr_sm[16][16];
    int g  = threadIdx.x >> 4;
    int gl = threadIdx.x & 15;
    int gidx = blockIdx.x * 16 + g;
    if (gidx >= lcnt[0]) return;
    int n = small_list[gidx];
    int r0 = rowptr[n];
    int deg = rowptr[n + 1] - r0;
    float adn = ad[n];

    float e = -INFINITY;
    int s = 0;
    if (gl < deg) { s = srcs[r0 + gl]; e = leaky(as[s] + adn); }
    sr_sm[g][gl] = s;
    float m = e;
    #pragma unroll
    for (int off = 8; off > 0; off >>= 1) m = fmaxf(m, __shfl_xor(m, off, 16));
    float sc = (gl < deg) ? __expf(e - m) : 0.f;
    float ssum = sc;
    #pragma unroll
    for (int off = 8; off > 0; off >>= 1) ssum += __shfl_xor(ssum, off, 16);
    al_sm[g][gl] = sc / ssum;

    int cbase = gl * 4;
    float a0 = 0.f, a1 = 0.f, a2 = 0.f, a3 = 0.f;
    for (int j = 0; j < deg; j += 4) {
      #pragma unroll
      for (int u = 0; u < 4; ++u) {
        int idx = j + u;
        bool vU = idx < deg;
        int jj = vU ? idx : 0;
        int   sU  = sr_sm[g][jj];
        float alU = vU ? al_sm[g][jj] : 0.f;
        uint2 hv = *(const uint2*)&Hm[(size_t)sU * 64 + cbase];
        float2 f0 = __half22float2(*(const __half2*)&hv.x);
        float2 f1 = __half22float2(*(const __half2*)&hv.y);
        a0 += f0.x * alU; a1 += f0.y * alU; a2 += f1.x * alU; a3 += f1.y * alU;
      }
    }
    float4 bv = *(const float4*)&bias[cbase];
    float4 o;
    o.x = a0 + bv.x; o.y = a1 + bv.y; o.z = a2 + bv.z; o.w = a3 + bv.w;
    *(float4*)&out[(size_t)n * 64 + cbase] = o;
    return;
  }
  __shared__ float al_sm[4][64];
  __shared__ int   sr_sm[4][64];
  int wv = threadIdx.x >> 6, lane = threadIdx.x & 63;
  int widx = (blockIdx.x - SB) * 4 + wv;
  if (widx >= lcnt[16]) return;
  int n = big_list[widx];
  int r0 = rowptr[n], r1 = rowptr[n + 1];
  int deg = r1 - r0;
  int grp = lane >> 4, gl = lane & 15;
  int cbase = gl * 4;
  float adn = ad[n];

  float a0 = 0.f, a1 = 0.f, a2 = 0.f, a3 = 0.f;

  if (deg <= 64) {
    float e = -INFINITY;
    int s = 0;
    if (lane < deg) { s = srcs[r0 + lane]; e = leaky(as[s] + adn); }
    sr_sm[wv][lane] = s;
    float m = e;
    #pragma unroll
    for (int off = 32; off > 0; off >>= 1) m = fmaxf(m, __shfl_xor(m, off));
    float sc = (lane < deg) ? __expf(e - m) : 0.f;
    float ssum = sc;
    #pragma unroll
    for (int off = 32; off > 0; off >>= 1) ssum += __shfl_xor(ssum, off);
    al_sm[wv][lane] = sc / ssum;

    for (int base = 0; base < deg; base += 16) {
      #pragma unroll
      for (int u = 0; u < 4; ++u) {
        int idx = base + grp * 4 + u;
        bool vU = idx < deg;
        int jj = vU ? idx : 0;
        int   sU  = sr_sm[wv][jj];
        float alU = vU ? al_sm[wv][jj] : 0.f;
        uint2 hv = *(const uint2*)&Hm[(size_t)sU * 64 + cbase];
        float2 f0 = __half22float2(*(const __half2*)&hv.x);
        float2 f1 = __half22float2(*(const __half2*)&hv.y);
        a0 += f0.x * alU; a1 += f0.y * alU; a2 += f1.x * alU; a3 += f1.y * alU;
      }
    }
  } else {
    float mh = -INFINITY;
    for (int r = r0 + lane; r < r1; r += 64)
      mh = fmaxf(mh, leaky(as[srcs[r]] + adn));
    #pragma unroll
    for (int off = 32; off > 0; off >>= 1) mh = fmaxf(mh, __shfl_xor(mh, off));
    float ssum = 0.f;
    for (int r = r0 + lane; r < r1; r += 64)
      ssum += __expf(leaky(as[srcs[r]] + adn) - mh);
    #pragma unroll
    for (int off = 32; off > 0; off >>= 1) ssum += __shfl_xor(ssum, off);
    float inv = 1.f / ssum;
    for (int r = r0; r < r1; r += 8) {
      int rA = r + grp, rB = rA + 4;
      bool vA = rA < r1, vB = rB < r1;
      int sA = srcs[vA ? rA : r0];
      int sB = srcs[vB ? rB : r0];
      float alA = vA ? (__expf(leaky(as[sA] + adn) - mh) * inv) : 0.f;
      float alB = vB ? (__expf(leaky(as[sB] + adn) - mh) * inv) : 0.f;
      uint2 hvA = *(const uint2*)&Hm[(size_t)sA * 64 + cbase];
      uint2 hvB = *(const uint2*)&Hm[(size_t)sB * 64 + cbase];
      float2 fA0 = __half22float2(*(const __half2*)&hvA.x);
      float2 fA1 = __half22float2(*(const __half2*)&hvA.y);
      float2 fB0 = __half22float2(*(const __half2*)&hvB.x);
      float2 fB1 = __half22float2(*(const __half2*)&hvB.y);
      a0 += fA0.x * alA + fB0.x * alB; a1 += fA0.y * alA + fB0.y * alB;
      a2 += fA1.x * alA + fB1.x * alB; a3 += fA1.y * alA + fB1.y * alB;
    }
  }
  a0 += __shfl_xor(a0, 16); a0 += __shfl_xor(a0, 32);
  a1 += __shfl_xor(a1, 16); a1 += __shfl_xor(a1, 32);
  a2 += __shfl_xor(a2, 16); a2 += __shfl_xor(a2, 32);
  a3 += __shfl_xor(a3, 16); a3 += __shfl_xor(a3, 32);
  if (grp == 0) {
    float4 bv = *(const float4*)&bias[cbase];
    float4 o;
    o.x = a0 + bv.x; o.y = a1 + bv.y; o.z = a2 + bv.z; o.w = a3 + bv.w;
    *(float4*)&out[(size_t)n * 64 + cbase] = o;
  }
}

extern "C" void kernel_launch(void* const* d_in, const int* in_sizes, int n_in,
                              void* d_out, int out_size, void* d_ws, size_t ws_size,
                              hipStream_t stream) {
  const float* x   = (const float*)d_in[0];
  const int*   ei  = (const int*)d_in[1];
  // d_in[2] edge_weight: unused by GATConv (edge_dim unset)
  const float* W1  = (const float*)d_in[3];
  const float* aS1 = (const float*)d_in[4];
  const float* aD1 = (const float*)d_in[5];
  const float* b1  = (const float*)d_in[6];
  const float* W2  = (const float*)d_in[7];
  const float* aS2 = (const float*)d_in[8];
  const float* aD2 = (const float*)d_in[9];
  const float* b2  = (const float*)d_in[10];

  const int N  = in_sizes[0] / 128;
  const int E  = in_sizes[2];
  const int ET = E + N;
  const int NB = (N + 127) >> 7;

  float* ws    = (float*)d_ws;
  __half* h1h  = (__half*)ws;                  // N*128 halfs
  __half* o1h  = (__half*)(ws + (size_t)N * 64);  // N*128 halfs (out1, fp16)
  float* as1   = ws + (size_t)N * 128;         // 4N
  float* ad1   = as1  + (size_t)4 * N;         // 4N
  float* as2   = ad1  + (size_t)4 * N;         // N
  float* ad2   = as2  + (size_t)N;             // N
  int*   lcnt    = (int*)(ad2 + (size_t)N);    // 32
  int*   rowptr  = lcnt + 32;                  // N+1
  int*   bbase   = rowptr + N + 1;             // NB+1
  int*   blkpref = bbase + NB + 1;             // NB*NBLKA
  int*   small_list = blkpref + NB * NBLKA;    // N
  int*   big_list   = small_list + N;          // N
  int*   srcs   = big_list + N;                // ET
  _Float16* w2t = (_Float16*)(srcs + ET);      // 64*128 halfs
  int*   pairs  = (int*)ws;                    // ET ints, aliased onto h1h... NO:
  // pairs aliases ws start == h1h, but h1h is written by the fused kernel while
  // passA writes pairs — they must not overlap in time. Order: fused kernel
  // writes h1h; passA writes pairs AFTER. pairs values consumed by passB before
  // agg1 reads h1h?? h1h written in fused (first), pairs written in passA
  // (second) would CORRUPT h1h. So pairs gets its own region now:
  int*   pairs_sep = (int*)(w2t + 64 * 128);   // ET ints (separate region)
  __half* h2h  = h1h;                          // alias (h1h dead after agg1)
  float* out  = (float*)d_out;                 // N*64

  const int gb = (N + 63) / 64;
  const int sb = (N + 15) / 16;
  const int bb = (N + 3) / 4;

  // ---- fused CSR histogram + GEMM1 (independent work, one launch) ----
  histc_gemm1_k<<<NBLKA + gb, 256, 0, stream>>>(ei, E, ET, blkpref, NB, W1, W2, w2t,
                                                x, aS1, aD1, h1h, as1, ad1, N);
  scan_blk_k<<<NB, 256, 0, stream>>>(blkpref, bbase);
  scan_bkt_k<<<1, 512, 0, stream>>>(bbase, lcnt, rowptr, NB, N, ET);
  passA_k<<<NBLKA, 256, 0, stream>>>(ei, E, ET, bbase, blkpref, pairs_sep, NB);
  passB_k<<<NB, 256, 0, stream>>>(pairs_sep, bbase, rowptr, srcs,
                                  small_list, big_list, lcnt, N);

  // ---- layer 1 aggregation ----
  agg1_k<<<sb + bb, 256, 0, stream>>>(rowptr, srcs, as1, ad1, h1h, b1, o1h,
                                      small_list, big_list, lcnt, sb);

  // ---- layer 2 ----
  gemm2_k<<<gb, 256, 0, stream>>>(o1h, w2t, aS2, aD2, h2h, as2, ad2, N);
  agg2_k<<<sb + bb, 256, 0, stream>>>(rowptr, srcs, as2, ad2, h2h, b2, out,
                                      small_list, big_list, lcnt, sb);
}

// Round 8
// 213.685 us; speedup vs baseline: 1.2074x; 1.0087x over previous
//
#include <hip/hip_runtime.h>
#include <hip/hip_fp16.h>
#include <math.h>

// GAT (2 layers) on MI355X — radix CSR + merged degree-bucketed aggregation.
// R1: gemm1/gemm2 MFMA (16x16x32 f16, fp32 accum).
// R5: histc+gemm1 fused (one launch, block-role split).        [215.5 us]
// R6: 3-way degree bucketing — NEW medium role (deg 17..32, 32-lane group,
//     2 nodes/wave). Poisson(17) puts ~53% of nodes there; big role was
//     wasting half a wave on them.
// R7: identical resubmit (R6 run was an infra failure, never executed).

#define NEG_SLOPE 0.2f
#define NBLKA 256
#define MAXNB 512
#define LDH 136   // padded halfs per LDS row

typedef _Float16 f16x8 __attribute__((ext_vector_type(8)));
typedef float f32x4 __attribute__((ext_vector_type(4)));
typedef unsigned int u32x4 __attribute__((ext_vector_type(4)));

__device__ __forceinline__ float leaky(float v) { return v > 0.f ? v : NEG_SLOPE * v; }

// ---------------- fused: CSR histogram (blocks < NBLKA) + GEMM1 (rest) ----------------
__global__ __launch_bounds__(256) void histc_gemm1_k(const int* __restrict__ ei, int E, int ET,
                                                     int* __restrict__ blkpref, int NB,
                                                     const float* __restrict__ W1,
                                                     const float* __restrict__ W2,
                                                     _Float16* __restrict__ w2t,
                                                     const float* __restrict__ X,
                                                     const float* __restrict__ aw_s,
                                                     const float* __restrict__ aw_d,
                                                     __half* __restrict__ Hh,
                                                     float* __restrict__ as,
                                                     float* __restrict__ ad, int N) {
  __shared__ float smemf[13056];   // 52224 B: gemm path xs+wt; hist path lhist
  int t = threadIdx.x;
  if (blockIdx.x < NBLKA) {
    // ---- histogram role ----
    int* lhist = (int*)smemf;
    int chunk = (ET + NBLKA - 1) / NBLKA;
    int e0 = blockIdx.x * chunk, e1 = min(ET, e0 + chunk);
    for (int b = t; b < NB; b += 256) lhist[b] = 0;
    __syncthreads();
    for (int e = e0 + t; e < e1; e += 256) {
      int d = (e < E) ? ei[E + e] : (e - E);
      atomicAdd(&lhist[d >> 7], 1);
    }
    __syncthreads();
    for (int b = t; b < NB; b += 256)
      blkpref[b * NBLKA + blockIdx.x] = lhist[b];
    // W2T [64n][128k] fp16 — block 0 only (consumed by gemm2, later launch)
    if (blockIdx.x == 0 && t < 64) {
      union { _Float16 h[8]; u32x4 u; } buf;
      for (int k0 = 0; k0 < 128; k0 += 8) {
        #pragma unroll
        for (int u = 0; u < 8; ++u) buf.h[u] = (_Float16)W2[(k0 + u) * 64 + t];
        *(u32x4*)&w2t[t * 128 + k0] = buf.u;
      }
    }
    return;
  }
  // ---- GEMM1 role: h1h = X(fp32->fp16) @ W1, + alpha1 ----
  _Float16* xs = (_Float16*)smemf;            // [64 * LDH]
  _Float16* wt = xs + 64 * LDH;               // [128 * LDH]
  int n0 = (blockIdx.x - NBLKA) * 64;
  // stage W1 transposed: W1 is [128k][128n] fp32; wt[n][k] fp16
  for (int i = t; i < 4096; i += 256) {
    int k = i >> 5, n4 = (i & 31) * 4;
    float4 wv = *(const float4*)&W1[k * 128 + n4];
    wt[(n4 + 0) * LDH + k] = (_Float16)wv.x;
    wt[(n4 + 1) * LDH + k] = (_Float16)wv.y;
    wt[(n4 + 2) * LDH + k] = (_Float16)wv.z;
    wt[(n4 + 3) * LDH + k] = (_Float16)wv.w;
  }
  // stage X fp32 -> fp16: 64 rows x 32 float4
  for (int i = t; i < 2048; i += 256) {
    int r = i >> 5, c4 = i & 31;
    int n = n0 + r;
    float4 xv = (n < N) ? *(const float4*)&X[(size_t)n * 128 + c4 * 4]
                        : make_float4(0.f, 0.f, 0.f, 0.f);
    __half2 h0 = __floats2half2_rn(xv.x, xv.y);
    __half2 h1 = __floats2half2_rn(xv.z, xv.w);
    uint2 u; u.x = *(unsigned*)&h0; u.y = *(unsigned*)&h1;
    *(uint2*)&xs[r * LDH + c4 * 4] = u;
  }
  __syncthreads();
  int wv = t >> 6, l = t & 63;
  int row16 = l & 15, kg = l >> 4;
  f32x4 acc[8];
  #pragma unroll
  for (int j = 0; j < 8; ++j) acc[j] = (f32x4){0.f, 0.f, 0.f, 0.f};
  #pragma unroll
  for (int kk = 0; kk < 4; ++kk) {
    int kbase = kk * 32 + kg * 8;
    f16x8 afr = *(f16x8*)&xs[(wv * 16 + row16) * LDH + kbase];
    #pragma unroll
    for (int j = 0; j < 8; ++j) {
      f16x8 bfr = *(f16x8*)&wt[(j * 16 + row16) * LDH + kbase];
      acc[j] = __builtin_amdgcn_mfma_f32_16x16x32_f16(afr, bfr, acc[j], 0, 0, 0);
    }
  }
  __syncthreads();
  #pragma unroll
  for (int j = 0; j < 8; ++j) {
    int col = j * 16 + row16;
    #pragma unroll
    for (int r = 0; r < 4; ++r) {
      int row = wv * 16 + kg * 4 + r;
      xs[row * LDH + col] = (_Float16)acc[j][r];
    }
  }
  __syncthreads();
  for (int i = t; i < 1024; i += 256) {
    int r = i >> 4, c8 = i & 15;
    int n = n0 + r;
    if (n < N) ((u32x4*)Hh)[(size_t)n * 16 + c8] = *(u32x4*)&xs[r * LDH + c8 * 8];
  }
  {
    int r = t >> 2, h = t & 3;
    int n = n0 + r;
    float ps = 0.f, pd = 0.f;
    #pragma unroll
    for (int q = 0; q < 4; ++q) {
      f16x8 hv = *(f16x8*)&xs[r * LDH + h * 32 + q * 8];
      float4 s0 = *(const float4*)&aw_s[h * 32 + q * 8];
      float4 s1 = *(const float4*)&aw_s[h * 32 + q * 8 + 4];
      float4 d0 = *(const float4*)&aw_d[h * 32 + q * 8];
      float4 d1 = *(const float4*)&aw_d[h * 32 + q * 8 + 4];
      ps += (float)hv[0] * s0.x + (float)hv[1] * s0.y + (float)hv[2] * s0.z + (float)hv[3] * s0.w
          + (float)hv[4] * s1.x + (float)hv[5] * s1.y + (float)hv[6] * s1.z + (float)hv[7] * s1.w;
      pd += (float)hv[0] * d0.x + (float)hv[1] * d0.y + (float)hv[2] * d0.z + (float)hv[3] * d0.w
          + (float)hv[4] * d1.x + (float)hv[5] * d1.y + (float)hv[6] * d1.z + (float)hv[7] * d1.w;
    }
    if (n < N) { as[n * 4 + h] = ps; ad[n * 4 + h] = pd; }
  }
}

__global__ __launch_bounds__(256) void scan_blk_k(int* __restrict__ blkpref,
                                                  int* __restrict__ bbase) {
  __shared__ int sm[NBLKA];
  int b = blockIdx.x, t = threadIdx.x;
  int v = blkpref[b * NBLKA + t];
  sm[t] = v;
  __syncthreads();
  #pragma unroll
  for (int off = 1; off < NBLKA; off <<= 1) {
    int x = (t >= off) ? sm[t - off] : 0;
    __syncthreads();
    sm[t] += x;
    __syncthreads();
  }
  blkpref[b * NBLKA + t] = sm[t] - v;
  if (t == NBLKA - 1) bbase[b] = sm[t];
}

__global__ __launch_bounds__(512) void scan_bkt_k(int* __restrict__ bbase,
                                                  int* __restrict__ lcnt,
                                                  int* __restrict__ rowptr,
                                                  int NB, int N, int ET) {
  __shared__ int sm[512];
  int t = threadIdx.x;
  int v = (t < NB) ? bbase[t] : 0;
  sm[t] = v;
  __syncthreads();
  #pragma unroll
  for (int off = 1; off < 512; off <<= 1) {
    int x = (t >= off) ? sm[t - off] : 0;
    __syncthreads();
    sm[t] += x;
    __syncthreads();
  }
  int excl = sm[t] - v;
  if (t <= NB) bbase[t] = excl;
  if (t == 0) { lcnt[0] = 0; lcnt[8] = 0; lcnt[16] = 0; rowptr[N] = ET; }
}

__global__ __launch_bounds__(256) void passA_k(const int* __restrict__ ei, int E, int ET,
                                               const int* __restrict__ bbase,
                                               const int* __restrict__ blkpref,
                                               int* __restrict__ pairs, int NB) {
  __shared__ int lcur[MAXNB];
  int chunk = (ET + NBLKA - 1) / NBLKA;
  int e0 = blockIdx.x * chunk, e1 = min(ET, e0 + chunk);
  for (int b = threadIdx.x; b < NB; b += 256)
    lcur[b] = bbase[b] + blkpref[b * NBLKA + blockIdx.x];
  __syncthreads();
  for (int e = e0 + threadIdx.x; e < e1; e += 256) {
    int s, d;
    if (e < E) { s = ei[e]; d = ei[E + e]; } else { s = d = e - E; }
    int b = d >> 7;
    int pos = atomicAdd(&lcur[b], 1);
    pairs[pos] = ((d & 127) << 17) | s;
  }
}

__global__ __launch_bounds__(256) void passB_k(const int* __restrict__ pairs,
                                               const int* __restrict__ bbase,
                                               int* __restrict__ rowptr,
                                               int* __restrict__ srcs,
                                               int* __restrict__ small_list,
                                               int* __restrict__ med_list,
                                               int* __restrict__ big_list,
                                               int* __restrict__ lcnt, int N) {
  __shared__ int ncnt[128], spre[128], lcur[128];
  __shared__ int wcS[2], wcM[2], wcB[2], bS, bM, bB;
  int b = blockIdx.x, t = threadIdx.x;
  int nb0 = b << 7;
  int nn = min(128, N - nb0);
  int e0 = bbase[b], e1 = bbase[b + 1];
  if (t < 128) ncnt[t] = 0;
  __syncthreads();
  for (int r = e0 + t; r < e1; r += 256)
    atomicAdd(&ncnt[pairs[r] >> 17], 1);
  __syncthreads();
  if (t < 128) spre[t] = ncnt[t];
  __syncthreads();
  #pragma unroll
  for (int off = 1; off < 128; off <<= 1) {
    int x = (t < 128 && t >= off) ? spre[t - off] : 0;
    __syncthreads();
    if (t < 128) spre[t] += x;
    __syncthreads();
  }
  if (t < nn) {
    int base = e0 + spre[t] - ncnt[t];
    rowptr[nb0 + t] = base;
    lcur[t] = base;
  }
  __syncthreads();
  for (int r = e0 + t; r < e1; r += 256) {
    int p = pairs[r];
    int pos = atomicAdd(&lcur[p >> 17], 1);
    srcs[pos] = p & 0x1FFFF;
  }
  int lane = t & 63, wv = t >> 6;
  bool valid = (t < nn);
  int deg = valid ? ncnt[t] : 0;
  bool isS = valid && (deg <= 16);
  bool isM = valid && (deg > 16) && (deg <= 32);
  bool isB = valid && (deg > 32);
  unsigned long long ms = __ballot(isS);
  unsigned long long mm = __ballot(isM);
  unsigned long long mbm = __ballot(isB);
  if (lane == 0 && wv < 2) {
    wcS[wv] = __popcll(ms); wcM[wv] = __popcll(mm); wcB[wv] = __popcll(mbm);
  }
  __syncthreads();
  if (t == 0) {
    bS = atomicAdd(&lcnt[0],  wcS[0] + wcS[1]);
    bM = atomicAdd(&lcnt[8],  wcM[0] + wcM[1]);
    bB = atomicAdd(&lcnt[16], wcB[0] + wcB[1]);
  }
  __syncthreads();
  unsigned long long below = (lane == 0) ? 0ull : (~0ull >> (64 - lane));
  int offS = bS + ((wv == 1) ? wcS[0] : 0);
  int offM = bM + ((wv == 1) ? wcM[0] : 0);
  int offB = bB + ((wv == 1) ? wcB[0] : 0);
  if (isS) small_list[offS + __popcll(ms & below)]  = nb0 + t;
  if (isM) med_list[offM + __popcll(mm & below)]    = nb0 + t;
  if (isB) big_list[offB + __popcll(mbm & below)]   = nb0 + t;
}

// ---------------- GEMM2 (MFMA) + alpha2: h2h = o1h(fp16) @ W2 ----------------
__global__ __launch_bounds__(256) void gemm2_k(const __half* __restrict__ X,
                                               const _Float16* __restrict__ WT,
                                               const float* __restrict__ aw_s,
                                               const float* __restrict__ aw_d,
                                               __half* __restrict__ Hh,
                                               float* __restrict__ as,
                                               float* __restrict__ ad, int N) {
  __shared__ _Float16 xs[64 * LDH];
  __shared__ _Float16 wt[64 * LDH];
  int t = threadIdx.x;
  int n0 = blockIdx.x * 64;
  for (int i = t; i < 1024; i += 256) {
    int r = i >> 4, c8 = i & 15;
    *(u32x4*)&wt[r * LDH + c8 * 8] = ((const u32x4*)WT)[i];
  }
  for (int i = t; i < 1024; i += 256) {
    int r = i >> 4, c8 = i & 15;
    int n = n0 + r;
    u32x4 v = (n < N) ? ((const u32x4*)X)[(size_t)n * 16 + c8] : (u32x4){0, 0, 0, 0};
    *(u32x4*)&xs[r * LDH + c8 * 8] = v;
  }
  __syncthreads();
  int wv = t >> 6, l = t & 63;
  int row16 = l & 15, kg = l >> 4;
  f32x4 acc[4];
  #pragma unroll
  for (int j = 0; j < 4; ++j) acc[j] = (f32x4){0.f, 0.f, 0.f, 0.f};
  #pragma unroll
  for (int kk = 0; kk < 4; ++kk) {
    int kbase = kk * 32 + kg * 8;
    f16x8 afr = *(f16x8*)&xs[(wv * 16 + row16) * LDH + kbase];
    #pragma unroll
    for (int j = 0; j < 4; ++j) {
      f16x8 bfr = *(f16x8*)&wt[(j * 16 + row16) * LDH + kbase];
      acc[j] = __builtin_amdgcn_mfma_f32_16x16x32_f16(afr, bfr, acc[j], 0, 0, 0);
    }
  }
  __syncthreads();
  #pragma unroll
  for (int j = 0; j < 4; ++j) {
    int col = j * 16 + row16;
    #pragma unroll
    for (int r = 0; r < 4; ++r) {
      int row = wv * 16 + kg * 4 + r;
      xs[row * LDH + col] = (_Float16)acc[j][r];
    }
  }
  __syncthreads();
  for (int i = t; i < 512; i += 256) {
    int r = i >> 3, c8 = i & 7;
    int n = n0 + r;
    if (n < N) ((u32x4*)Hh)[(size_t)n * 8 + c8] = *(u32x4*)&xs[r * LDH + c8 * 8];
  }
  {
    int r = t >> 2, q = t & 3;
    int n = n0 + r;
    float ps = 0.f, pd = 0.f;
    #pragma unroll
    for (int qq = 0; qq < 2; ++qq) {
      f16x8 hv = *(f16x8*)&xs[r * LDH + q * 16 + qq * 8];
      float4 s0 = *(const float4*)&aw_s[q * 16 + qq * 8];
      float4 s1 = *(const float4*)&aw_s[q * 16 + qq * 8 + 4];
      float4 d0 = *(const float4*)&aw_d[q * 16 + qq * 8];
      float4 d1 = *(const float4*)&aw_d[q * 16 + qq * 8 + 4];
      ps += (float)hv[0] * s0.x + (float)hv[1] * s0.y + (float)hv[2] * s0.z + (float)hv[3] * s0.w
          + (float)hv[4] * s1.x + (float)hv[5] * s1.y + (float)hv[6] * s1.z + (float)hv[7] * s1.w;
      pd += (float)hv[0] * d0.x + (float)hv[1] * d0.y + (float)hv[2] * d0.z + (float)hv[3] * d0.w
          + (float)hv[4] * d1.x + (float)hv[5] * d1.y + (float)hv[6] * d1.z + (float)hv[7] * d1.w;
    }
    ps += __shfl_xor(ps, 1); ps += __shfl_xor(ps, 2);
    pd += __shfl_xor(pd, 1); pd += __shfl_xor(pd, 2);
    if (q == 0 && n < N) { as[n] = ps; ad[n] = pd; }
  }
}

__device__ __forceinline__ void load8h(const __half* p, float* f) {
  uint4 hv = *(const uint4*)p;
  float2 f0 = __half22float2(*(const __half2*)&hv.x);
  float2 f1 = __half22float2(*(const __half2*)&hv.y);
  float2 f2 = __half22float2(*(const __half2*)&hv.z);
  float2 f3 = __half22float2(*(const __half2*)&hv.w);
  f[0] = f0.x; f[1] = f0.y; f[2] = f1.x; f[3] = f1.y;
  f[4] = f2.x; f[5] = f2.y; f[6] = f3.x; f[7] = f3.y;
}

// ---------------- layer-1 merged aggregation (out fp16) ----------------
__global__ __launch_bounds__(256) void agg1_k(const int* __restrict__ rowptr,
                                              const int* __restrict__ srcs,
                                              const float* __restrict__ as,
                                              const float* __restrict__ ad,
                                              const __half* __restrict__ Hm,
                                              const float* __restrict__ bias,
                                              __half* __restrict__ out,
                                              const int* __restrict__ small_list,
                                              const int* __restrict__ med_list,
                                              const int* __restrict__ big_list,
                                              const int* __restrict__ lcnt,
                                              int SB, int MB) {
  if (blockIdx.x < (unsigned)SB) {
    // ---- small role: deg<=16, node per 16-lane group ----
    __shared__ float al_sm[16][17][4];
    __shared__ int   sr_sm[16][16];
    int g  = threadIdx.x >> 4;
    int gl = threadIdx.x & 15;
    int gidx = blockIdx.x * 16 + g;
    if (gidx >= lcnt[0]) return;
    int n = small_list[gidx];
    int r0 = rowptr[n];
    int deg = rowptr[n + 1] - r0;
    float4 adn = *(const float4*)&ad[n * 4];

    float e0 = -INFINITY, e1 = -INFINITY, e2 = -INFINITY, e3 = -INFINITY;
    int s = 0;
    if (gl < deg) {
      s = srcs[r0 + gl];
      float4 av = *(const float4*)&as[s * 4];
      e0 = leaky(av.x + adn.x); e1 = leaky(av.y + adn.y);
      e2 = leaky(av.z + adn.z); e3 = leaky(av.w + adn.w);
    }
    sr_sm[g][gl] = s;
    float m0 = e0, m1 = e1, m2 = e2, m3 = e3;
    #pragma unroll
    for (int off = 8; off > 0; off >>= 1) {
      m0 = fmaxf(m0, __shfl_xor(m0, off, 16)); m1 = fmaxf(m1, __shfl_xor(m1, off, 16));
      m2 = fmaxf(m2, __shfl_xor(m2, off, 16)); m3 = fmaxf(m3, __shfl_xor(m3, off, 16));
    }
    float sc0 = (gl < deg) ? __expf(e0 - m0) : 0.f;
    float sc1 = (gl < deg) ? __expf(e1 - m1) : 0.f;
    float sc2 = (gl < deg) ? __expf(e2 - m2) : 0.f;
    float sc3 = (gl < deg) ? __expf(e3 - m3) : 0.f;
    float s0 = sc0, s1 = sc1, s2 = sc2, s3 = sc3;
    #pragma unroll
    for (int off = 8; off > 0; off >>= 1) {
      s0 += __shfl_xor(s0, off, 16); s1 += __shfl_xor(s1, off, 16);
      s2 += __shfl_xor(s2, off, 16); s3 += __shfl_xor(s3, off, 16);
    }
    *(float4*)&al_sm[g][gl][0] =
        make_float4(sc0 / s0, sc1 / s1, sc2 / s2, sc3 / s3);

    int h = gl >> 2;
    int cbase = gl * 8;
    float a0 = 0.f, a1 = 0.f, a2 = 0.f, a3 = 0.f,
          a4 = 0.f, a5 = 0.f, a6 = 0.f, a7 = 0.f;
    for (int j = 0; j < deg; j += 4) {
      #pragma unroll
      for (int u = 0; u < 4; ++u) {
        int idx = j + u;
        bool vU = idx < deg;
        int jj = vU ? idx : 0;
        int   sU  = sr_sm[g][jj];
        float alU = vU ? al_sm[g][jj][h] : 0.f;
        float f[8];
        load8h(&Hm[(size_t)sU * 128 + cbase], f);
        a0 += f[0] * alU; a1 += f[1] * alU; a2 += f[2] * alU; a3 += f[3] * alU;
        a4 += f[4] * alU; a5 += f[5] * alU; a6 += f[6] * alU; a7 += f[7] * alU;
      }
    }
    float4 b0 = *(const float4*)&bias[cbase];
    float4 b1 = *(const float4*)&bias[cbase + 4];
    __half2* dst = (__half2*)&out[(size_t)n * 128 + cbase];
    dst[0] = __floats2half2_rn(fmaxf(a0 + b0.x, 0.f), fmaxf(a1 + b0.y, 0.f));
    dst[1] = __floats2half2_rn(fmaxf(a2 + b0.z, 0.f), fmaxf(a3 + b0.w, 0.f));
    dst[2] = __floats2half2_rn(fmaxf(a4 + b1.x, 0.f), fmaxf(a5 + b1.y, 0.f));
    dst[3] = __floats2half2_rn(fmaxf(a6 + b1.z, 0.f), fmaxf(a7 + b1.w, 0.f));
    return;
  }
  if (blockIdx.x < (unsigned)(SB + MB)) {
    // ---- medium role: deg 17..32, node per 32-lane group (8/block) ----
    __shared__ float al_sm[8][33][4];
    __shared__ int   sr_sm[8][32];
    int g   = threadIdx.x >> 5;
    int l32 = threadIdx.x & 31;
    int gidx = (blockIdx.x - SB) * 8 + g;
    if (gidx >= lcnt[8]) return;
    int n = med_list[gidx];
    int r0 = rowptr[n];
    int deg = rowptr[n + 1] - r0;
    float4 adn = *(const float4*)&ad[n * 4];

    float e0 = -INFINITY, e1 = -INFINITY, e2 = -INFINITY, e3 = -INFINITY;
    int s = 0;
    if (l32 < deg) {
      s = srcs[r0 + l32];
      float4 av = *(const float4*)&as[s * 4];
      e0 = leaky(av.x + adn.x); e1 = leaky(av.y + adn.y);
      e2 = leaky(av.z + adn.z); e3 = leaky(av.w + adn.w);
    }
    sr_sm[g][l32] = s;
    float m0 = e0, m1 = e1, m2 = e2, m3 = e3;
    #pragma unroll
    for (int off = 16; off > 0; off >>= 1) {
      m0 = fmaxf(m0, __shfl_xor(m0, off, 32)); m1 = fmaxf(m1, __shfl_xor(m1, off, 32));
      m2 = fmaxf(m2, __shfl_xor(m2, off, 32)); m3 = fmaxf(m3, __shfl_xor(m3, off, 32));
    }
    float sc0 = (l32 < deg) ? __expf(e0 - m0) : 0.f;
    float sc1 = (l32 < deg) ? __expf(e1 - m1) : 0.f;
    float sc2 = (l32 < deg) ? __expf(e2 - m2) : 0.f;
    float sc3 = (l32 < deg) ? __expf(e3 - m3) : 0.f;
    float s0 = sc0, s1 = sc1, s2 = sc2, s3 = sc3;
    #pragma unroll
    for (int off = 16; off > 0; off >>= 1) {
      s0 += __shfl_xor(s0, off, 32); s1 += __shfl_xor(s1, off, 32);
      s2 += __shfl_xor(s2, off, 32); s3 += __shfl_xor(s3, off, 32);
    }
    *(float4*)&al_sm[g][l32][0] =
        make_float4(sc0 / s0, sc1 / s1, sc2 / s2, sc3 / s3);

    int cl = l32 & 15, grp2 = l32 >> 4, h = cl >> 2;
    int cbase = cl * 8;
    float a0 = 0.f, a1 = 0.f, a2 = 0.f, a3 = 0.f,
          a4 = 0.f, a5 = 0.f, a6 = 0.f, a7 = 0.f;
    for (int base = 0; base < deg; base += 8) {
      #pragma unroll
      for (int u = 0; u < 4; ++u) {
        int idx = base + grp2 * 4 + u;
        bool vU = idx < deg;
        int jj = vU ? idx : 0;
        int   sU  = sr_sm[g][jj];
        float alU = vU ? al_sm[g][jj][h] : 0.f;
        float f[8];
        load8h(&Hm[(size_t)sU * 128 + cbase], f);
        a0 += f[0] * alU; a1 += f[1] * alU; a2 += f[2] * alU; a3 += f[3] * alU;
        a4 += f[4] * alU; a5 += f[5] * alU; a6 += f[6] * alU; a7 += f[7] * alU;
      }
    }
    a0 += __shfl_xor(a0, 16); a1 += __shfl_xor(a1, 16);
    a2 += __shfl_xor(a2, 16); a3 += __shfl_xor(a3, 16);
    a4 += __shfl_xor(a4, 16); a5 += __shfl_xor(a5, 16);
    a6 += __shfl_xor(a6, 16); a7 += __shfl_xor(a7, 16);
    if (grp2 == 0) {
      float4 b0 = *(const float4*)&bias[cbase];
      float4 b1 = *(const float4*)&bias[cbase + 4];
      __half2* dst = (__half2*)&out[(size_t)n * 128 + cbase];
      dst[0] = __floats2half2_rn(fmaxf(a0 + b0.x, 0.f), fmaxf(a1 + b0.y, 0.f));
      dst[1] = __floats2half2_rn(fmaxf(a2 + b0.z, 0.f), fmaxf(a3 + b0.w, 0.f));
      dst[2] = __floats2half2_rn(fmaxf(a4 + b1.x, 0.f), fmaxf(a5 + b1.y, 0.f));
      dst[3] = __floats2half2_rn(fmaxf(a6 + b1.z, 0.f), fmaxf(a7 + b1.w, 0.f));
    }
    return;
  }
  // ---- big role: deg>32, node per wave ----
  __shared__ float al_sm[4][64][4];
  __shared__ int   sr_sm[4][64];
  int wv = threadIdx.x >> 6, lane = threadIdx.x & 63;
  int widx = (blockIdx.x - SB - MB) * 4 + wv;
  if (widx >= lcnt[16]) return;
  int n = big_list[widx];
  int r0 = rowptr[n], r1 = rowptr[n + 1];
  int deg = r1 - r0;
  int grp = lane >> 4, gl = lane & 15, h = gl >> 2;
  int cbase = gl * 8;
  float4 adn = *(const float4*)&ad[n * 4];

  float a0 = 0.f, a1 = 0.f, a2 = 0.f, a3 = 0.f,
        a4 = 0.f, a5 = 0.f, a6 = 0.f, a7 = 0.f;

  if (deg <= 64) {
    float e0 = -INFINITY, e1 = -INFINITY, e2 = -INFINITY, e3 = -INFINITY;
    int s = 0;
    if (lane < deg) {
      s = srcs[r0 + lane];
      float4 av = *(const float4*)&as[s * 4];
      e0 = leaky(av.x + adn.x); e1 = leaky(av.y + adn.y);
      e2 = leaky(av.z + adn.z); e3 = leaky(av.w + adn.w);
    }
    sr_sm[wv][lane] = s;
    float m0 = e0, m1 = e1, m2 = e2, m3 = e3;
    #pragma unroll
    for (int off = 32; off > 0; off >>= 1) {
      m0 = fmaxf(m0, __shfl_xor(m0, off)); m1 = fmaxf(m1, __shfl_xor(m1, off));
      m2 = fmaxf(m2, __shfl_xor(m2, off)); m3 = fmaxf(m3, __shfl_xor(m3, off));
    }
    float sc0 = (lane < deg) ? __expf(e0 - m0) : 0.f;
    float sc1 = (lane < deg) ? __expf(e1 - m1) : 0.f;
    float sc2 = (lane < deg) ? __expf(e2 - m2) : 0.f;
    float sc3 = (lane < deg) ? __expf(e3 - m3) : 0.f;
    float s0 = sc0, s1 = sc1, s2 = sc2, s3 = sc3;
    #pragma unroll
    for (int off = 32; off > 0; off >>= 1) {
      s0 += __shfl_xor(s0, off); s1 += __shfl_xor(s1, off);
      s2 += __shfl_xor(s2, off); s3 += __shfl_xor(s3, off);
    }
    *(float4*)&al_sm[wv][lane][0] =
        make_float4(sc0 / s0, sc1 / s1, sc2 / s2, sc3 / s3);

    for (int base = 0; base < deg; base += 16) {
      #pragma unroll
      for (int u = 0; u < 4; ++u) {
        int idx = base + grp * 4 + u;
        bool vU = idx < deg;
        int jj = vU ? idx : 0;
        int   sU  = sr_sm[wv][jj];
        float alU = vU ? al_sm[wv][jj][h] : 0.f;
        float f[8];
        load8h(&Hm[(size_t)sU * 128 + cbase], f);
        a0 += f[0] * alU; a1 += f[1] * alU; a2 += f[2] * alU; a3 += f[3] * alU;
        a4 += f[4] * alU; a5 += f[5] * alU; a6 += f[6] * alU; a7 += f[7] * alU;
      }
    }
  } else {
    float m0 = -INFINITY, m1 = -INFINITY, m2 = -INFINITY, m3 = -INFINITY;
    for (int r = r0 + lane; r < r1; r += 64) {
      int s = srcs[r];
      float4 av = *(const float4*)&as[s * 4];
      m0 = fmaxf(m0, leaky(av.x + adn.x)); m1 = fmaxf(m1, leaky(av.y + adn.y));
      m2 = fmaxf(m2, leaky(av.z + adn.z)); m3 = fmaxf(m3, leaky(av.w + adn.w));
    }
    #pragma unroll
    for (int off = 32; off > 0; off >>= 1) {
      m0 = fmaxf(m0, __shfl_xor(m0, off)); m1 = fmaxf(m1, __shfl_xor(m1, off));
      m2 = fmaxf(m2, __shfl_xor(m2, off)); m3 = fmaxf(m3, __shfl_xor(m3, off));
    }
    float s0 = 0.f, s1 = 0.f, s2 = 0.f, s3 = 0.f;
    for (int r = r0 + lane; r < r1; r += 64) {
      int s = srcs[r];
      float4 av = *(const float4*)&as[s * 4];
      s0 += __expf(leaky(av.x + adn.x) - m0); s1 += __expf(leaky(av.y + adn.y) - m1);
      s2 += __expf(leaky(av.z + adn.z) - m2); s3 += __expf(leaky(av.w + adn.w) - m3);
    }
    #pragma unroll
    for (int off = 32; off > 0; off >>= 1) {
      s0 += __shfl_xor(s0, off); s1 += __shfl_xor(s1, off);
      s2 += __shfl_xor(s2, off); s3 += __shfl_xor(s3, off);
    }
    float mhh = (h == 0) ? m0 : (h == 1) ? m1 : (h == 2) ? m2 : m3;
    float inv = 1.f / ((h == 0) ? s0 : (h == 1) ? s1 : (h == 2) ? s2 : s3);
    float adh = (h == 0) ? adn.x : (h == 1) ? adn.y : (h == 2) ? adn.z : adn.w;
    for (int r = r0; r < r1; r += 8) {
      int rA = r + grp, rB = rA + 4;
      bool vA = rA < r1, vB = rB < r1;
      int sA = srcs[vA ? rA : r0];
      int sB = srcs[vB ? rB : r0];
      float avA = as[sA * 4 + h], avB = as[sB * 4 + h];
      float alA = vA ? (__expf(leaky(avA + adh) - mhh) * inv) : 0.f;
      float alB = vB ? (__expf(leaky(avB + adh) - mhh) * inv) : 0.f;
      float fA[8], fB[8];
      load8h(&Hm[(size_t)sA * 128 + cbase], fA);
      load8h(&Hm[(size_t)sB * 128 + cbase], fB);
      a0 += fA[0] * alA + fB[0] * alB; a1 += fA[1] * alA + fB[1] * alB;
      a2 += fA[2] * alA + fB[2] * alB; a3 += fA[3] * alA + fB[3] * alB;
      a4 += fA[4] * alA + fB[4] * alB; a5 += fA[5] * alA + fB[5] * alB;
      a6 += fA[6] * alA + fB[6] * alB; a7 += fA[7] * alA + fB[7] * alB;
    }
  }
  a0 += __shfl_xor(a0, 16); a0 += __shfl_xor(a0, 32);
  a1 += __shfl_xor(a1, 16); a1 += __shfl_xor(a1, 32);
  a2 += __shfl_xor(a2, 16); a2 += __shfl_xor(a2, 32);
  a3 += __shfl_xor(a3, 16); a3 += __shfl_xor(a3, 32);
  a4 += __shfl_xor(a4, 16); a4 += __shfl_xor(a4, 32);
  a5 += __shfl_xor(a5, 16); a5 += __shfl_xor(a5, 32);
  a6 += __shfl_xor(a6, 16); a6 += __shfl_xor(a6, 32);
  a7 += __shfl_xor(a7, 16); a7 += __shfl_xor(a7, 32);
  if (grp == 0) {
    float4 b0 = *(const float4*)&bias[cbase];
    float4 b1 = *(const float4*)&bias[cbase + 4];
    __half2* dst = (__half2*)&out[(size_t)n * 128 + cbase];
    dst[0] = __floats2half2_rn(fmaxf(a0 + b0.x, 0.f), fmaxf(a1 + b0.y, 0.f));
    dst[1] = __floats2half2_rn(fmaxf(a2 + b0.z, 0.f), fmaxf(a3 + b0.w, 0.f));
    dst[2] = __floats2half2_rn(fmaxf(a4 + b1.x, 0.f), fmaxf(a5 + b1.y, 0.f));
    dst[3] = __floats2half2_rn(fmaxf(a6 + b1.z, 0.f), fmaxf(a7 + b1.w, 0.f));
  }
}

// ---------------- layer-2 merged aggregation (out fp32 = d_out) ----------------
__global__ __launch_bounds__(256) void agg2_k(const int* __restrict__ rowptr,
                                              const int* __restrict__ srcs,
                                              const float* __restrict__ as,
                                              const float* __restrict__ ad,
                                              const __half* __restrict__ Hm,
                                              const float* __restrict__ bias,
                                              float* __restrict__ out,
                                              const int* __restrict__ small_list,
                                              const int* __restrict__ med_list,
                                              const int* __restrict__ big_list,
                                              const int* __restrict__ lcnt,
                                              int SB, int MB) {
  if (blockIdx.x < (unsigned)SB) {
    __shared__ float al_sm[16][17];
    __shared__ int   sr_sm[16][16];
    int g  = threadIdx.x >> 4;
    int gl = threadIdx.x & 15;
    int gidx = blockIdx.x * 16 + g;
    if (gidx >= lcnt[0]) return;
    int n = small_list[gidx];
    int r0 = rowptr[n];
    int deg = rowptr[n + 1] - r0;
    float adn = ad[n];

    float e = -INFINITY;
    int s = 0;
    if (gl < deg) { s = srcs[r0 + gl]; e = leaky(as[s] + adn); }
    sr_sm[g][gl] = s;
    float m = e;
    #pragma unroll
    for (int off = 8; off > 0; off >>= 1) m = fmaxf(m, __shfl_xor(m, off, 16));
    float sc = (gl < deg) ? __expf(e - m) : 0.f;
    float ssum = sc;
    #pragma unroll
    for (int off = 8; off > 0; off >>= 1) ssum += __shfl_xor(ssum, off, 16);
    al_sm[g][gl] = sc / ssum;

    int cbase = gl * 4;
    float a0 = 0.f, a1 = 0.f, a2 = 0.f, a3 = 0.f;
    for (int j = 0; j < deg; j += 4) {
      #pragma unroll
      for (int u = 0; u < 4; ++u) {
        int idx = j + u;
        bool vU = idx < deg;
        int jj = vU ? idx : 0;
        int   sU  = sr_sm[g][jj];
        float alU = vU ? al_sm[g][jj] : 0.f;
        uint2 hv = *(const uint2*)&Hm[(size_t)sU * 64 + cbase];
        float2 f0 = __half22float2(*(const __half2*)&hv.x);
        float2 f1 = __half22float2(*(const __half2*)&hv.y);
        a0 += f0.x * alU; a1 += f0.y * alU; a2 += f1.x * alU; a3 += f1.y * alU;
      }
    }
    float4 bv = *(const float4*)&bias[cbase];
    float4 o;
    o.x = a0 + bv.x; o.y = a1 + bv.y; o.z = a2 + bv.z; o.w = a3 + bv.w;
    *(float4*)&out[(size_t)n * 64 + cbase] = o;
    return;
  }
  if (blockIdx.x < (unsigned)(SB + MB)) {
    // ---- medium role: deg 17..32, node per 32-lane group ----
    __shared__ float al_sm[8][33];
    __shared__ int   sr_sm[8][32];
    int g   = threadIdx.x >> 5;
    int l32 = threadIdx.x & 31;
    int gidx = (blockIdx.x - SB) * 8 + g;
    if (gidx >= lcnt[8]) return;
    int n = med_list[gidx];
    int r0 = rowptr[n];
    int deg = rowptr[n + 1] - r0;
    float adn = ad[n];

    float e = -INFINITY;
    int s = 0;
    if (l32 < deg) { s = srcs[r0 + l32]; e = leaky(as[s] + adn); }
    sr_sm[g][l32] = s;
    float m = e;
    #pragma unroll
    for (int off = 16; off > 0; off >>= 1) m = fmaxf(m, __shfl_xor(m, off, 32));
    float sc = (l32 < deg) ? __expf(e - m) : 0.f;
    float ssum = sc;
    #pragma unroll
    for (int off = 16; off > 0; off >>= 1) ssum += __shfl_xor(ssum, off, 32);
    al_sm[g][l32] = sc / ssum;

    int cl = l32 & 15, grp2 = l32 >> 4;
    int cbase = cl * 4;
    float a0 = 0.f, a1 = 0.f, a2 = 0.f, a3 = 0.f;
    for (int base = 0; base < deg; base += 8) {
      #pragma unroll
      for (int u = 0; u < 4; ++u) {
        int idx = base + grp2 * 4 + u;
        bool vU = idx < deg;
        int jj = vU ? idx : 0;
        int   sU  = sr_sm[g][jj];
        float alU = vU ? al_sm[g][jj] : 0.f;
        uint2 hv = *(const uint2*)&Hm[(size_t)sU * 64 + cbase];
        float2 f0 = __half22float2(*(const __half2*)&hv.x);
        float2 f1 = __half22float2(*(const __half2*)&hv.y);
        a0 += f0.x * alU; a1 += f0.y * alU; a2 += f1.x * alU; a3 += f1.y * alU;
      }
    }
    a0 += __shfl_xor(a0, 16); a1 += __shfl_xor(a1, 16);
    a2 += __shfl_xor(a2, 16); a3 += __shfl_xor(a3, 16);
    if (grp2 == 0) {
      float4 bv = *(const float4*)&bias[cbase];
      float4 o;
      o.x = a0 + bv.x; o.y = a1 + bv.y; o.z = a2 + bv.z; o.w = a3 + bv.w;
      *(float4*)&out[(size_t)n * 64 + cbase] = o;
    }
    return;
  }
  __shared__ float al_sm[4][64];
  __shared__ int   sr_sm[4][64];
  int wv = threadIdx.x >> 6, lane = threadIdx.x & 63;
  int widx = (blockIdx.x - SB - MB) * 4 + wv;
  if (widx >= lcnt[16]) return;
  int n = big_list[widx];
  int r0 = rowptr[n], r1 = rowptr[n + 1];
  int deg = r1 - r0;
  int grp = lane >> 4, gl = lane & 15;
  int cbase = gl * 4;
  float adn = ad[n];

  float a0 = 0.f, a1 = 0.f, a2 = 0.f, a3 = 0.f;

  if (deg <= 64) {
    float e = -INFINITY;
    int s = 0;
    if (lane < deg) { s = srcs[r0 + lane]; e = leaky(as[s] + adn); }
    sr_sm[wv][lane] = s;
    float m = e;
    #pragma unroll
    for (int off = 32; off > 0; off >>= 1) m = fmaxf(m, __shfl_xor(m, off));
    float sc = (lane < deg) ? __expf(e - m) : 0.f;
    float ssum = sc;
    #pragma unroll
    for (int off = 32; off > 0; off >>= 1) ssum += __shfl_xor(ssum, off);
    al_sm[wv][lane] = sc / ssum;

    for (int base = 0; base < deg; base += 16) {
      #pragma unroll
      for (int u = 0; u < 4; ++u) {
        int idx = base + grp * 4 + u;
        bool vU = idx < deg;
        int jj = vU ? idx : 0;
        int   sU  = sr_sm[wv][jj];
        float alU = vU ? al_sm[wv][jj] : 0.f;
        uint2 hv = *(const uint2*)&Hm[(size_t)sU * 64 + cbase];
        float2 f0 = __half22float2(*(const __half2*)&hv.x);
        float2 f1 = __half22float2(*(const __half2*)&hv.y);
        a0 += f0.x * alU; a1 += f0.y * alU; a2 += f1.x * alU; a3 += f1.y * alU;
      }
    }
  } else {
    float mh = -INFINITY;
    for (int r = r0 + lane; r < r1; r += 64)
      mh = fmaxf(mh, leaky(as[srcs[r]] + adn));
    #pragma unroll
    for (int off = 32; off > 0; off >>= 1) mh = fmaxf(mh, __shfl_xor(mh, off));
    float ssum = 0.f;
    for (int r = r0 + lane; r < r1; r += 64)
      ssum += __expf(leaky(as[srcs[r]] + adn) - mh);
    #pragma unroll
    for (int off = 32; off > 0; off >>= 1) ssum += __shfl_xor(ssum, off);
    float inv = 1.f / ssum;
    for (int r = r0; r < r1; r += 8) {
      int rA = r + grp, rB = rA + 4;
      bool vA = rA < r1, vB = rB < r1;
      int sA = srcs[vA ? rA : r0];
      int sB = srcs[vB ? rB : r0];
      float alA = vA ? (__expf(leaky(as[sA] + adn) - mh) * inv) : 0.f;
      float alB = vB ? (__expf(leaky(as[sB] + adn) - mh) * inv) : 0.f;
      uint2 hvA = *(const uint2*)&Hm[(size_t)sA * 64 + cbase];
      uint2 hvB = *(const uint2*)&Hm[(size_t)sB * 64 + cbase];
      float2 fA0 = __half22float2(*(const __half2*)&hvA.x);
      float2 fA1 = __half22float2(*(const __half2*)&hvA.y);
      float2 fB0 = __half22float2(*(const __half2*)&hvB.x);
      float2 fB1 = __half22float2(*(const __half2*)&hvB.y);
      a0 += fA0.x * alA + fB0.x * alB; a1 += fA0.y * alA + fB0.y * alB;
      a2 += fA1.x * alA + fB1.x * alB; a3 += fA1.y * alA + fB1.y * alB;
    }
  }
  a0 += __shfl_xor(a0, 16); a0 += __shfl_xor(a0, 32);
  a1 += __shfl_xor(a1, 16); a1 += __shfl_xor(a1, 32);
  a2 += __shfl_xor(a2, 16); a2 += __shfl_xor(a2, 32);
  a3 += __shfl_xor(a3, 16); a3 += __shfl_xor(a3, 32);
  if (grp == 0) {
    float4 bv = *(const float4*)&bias[cbase];
    float4 o;
    o.x = a0 + bv.x; o.y = a1 + bv.y; o.z = a2 + bv.z; o.w = a3 + bv.w;
    *(float4*)&out[(size_t)n * 64 + cbase] = o;
  }
}

extern "C" void kernel_launch(void* const* d_in, const int* in_sizes, int n_in,
                              void* d_out, int out_size, void* d_ws, size_t ws_size,
                              hipStream_t stream) {
  const float* x   = (const float*)d_in[0];
  const int*   ei  = (const int*)d_in[1];
  // d_in[2] edge_weight: unused by GATConv (edge_dim unset)
  const float* W1  = (const float*)d_in[3];
  const float* aS1 = (const float*)d_in[4];
  const float* aD1 = (const float*)d_in[5];
  const float* b1  = (const float*)d_in[6];
  const float* W2  = (const float*)d_in[7];
  const float* aS2 = (const float*)d_in[8];
  const float* aD2 = (const float*)d_in[9];
  const float* b2  = (const float*)d_in[10];

  const int N  = in_sizes[0] / 128;
  const int E  = in_sizes[2];
  const int ET = E + N;
  const int NB = (N + 127) >> 7;

  float* ws    = (float*)d_ws;
  __half* h1h  = (__half*)ws;                  // N*128 halfs
  __half* o1h  = (__half*)(ws + (size_t)N * 64);  // N*128 halfs (out1, fp16)
  float* as1   = ws + (size_t)N * 128;         // 4N
  float* ad1   = as1  + (size_t)4 * N;         // 4N
  float* as2   = ad1  + (size_t)4 * N;         // N
  float* ad2   = as2  + (size_t)N;             // N
  int*   lcnt    = (int*)(ad2 + (size_t)N);    // 32
  int*   rowptr  = lcnt + 32;                  // N+1
  int*   bbase   = rowptr + N + 1;             // NB+1
  int*   blkpref = bbase + NB + 1;             // NB*NBLKA
  int*   small_list = blkpref + NB * NBLKA;    // N
  int*   med_list   = small_list + N;          // N
  int*   big_list   = med_list + N;            // N
  int*   srcs   = big_list + N;                // ET
  _Float16* w2t = (_Float16*)(srcs + ET);      // 64*128 halfs
  int*   pairs_sep = (int*)(w2t + 64 * 128);   // ET ints (separate region)
  __half* h2h  = h1h;                          // alias (h1h dead after agg1)
  float* out  = (float*)d_out;                 // N*64

  const int gb = (N + 63) / 64;
  const int sb = (N + 15) / 16;
  const int mb = (N + 7) / 8;
  const int bb = (N + 3) / 4;

  // ---- fused CSR histogram + GEMM1 (independent work, one launch) ----
  histc_gemm1_k<<<NBLKA + gb, 256, 0, stream>>>(ei, E, ET, blkpref, NB, W1, W2, w2t,
                                                x, aS1, aD1, h1h, as1, ad1, N);
  scan_blk_k<<<NB, 256, 0, stream>>>(blkpref, bbase);
  scan_bkt_k<<<1, 512, 0, stream>>>(bbase, lcnt, rowptr, NB, N, ET);
  passA_k<<<NBLKA, 256, 0, stream>>>(ei, E, ET, bbase, blkpref, pairs_sep, NB);
  passB_k<<<NB, 256, 0, stream>>>(pairs_sep, bbase, rowptr, srcs,
                                  small_list, med_list, big_list, lcnt, N);

  // ---- layer 1 aggregation ----
  agg1_k<<<sb + mb + bb, 256, 0, stream>>>(rowptr, srcs, as1, ad1, h1h, b1, o1h,
                                           small_list, med_list, big_list, lcnt, sb, mb);

  // ---- layer 2 ----
  gemm2_k<<<gb, 256, 0, stream>>>(o1h, w2t, aS2, aD2, h2h, as2, ad2, N);
  agg2_k<<<sb + mb + bb, 256, 0, stream>>>(rowptr, srcs, as2, ad2, h2h, b2, out,
                                           small_list, med_list, big_list, lcnt, sb, mb);
}